// Round 13
// baseline (719.731 us; speedup 1.0000x reference)
//
#include <hip/hip_runtime.h>
#include <hip/hip_bf16.h>
#include <math.h>

#define DD 64
#define HIDC 128
#define FN 92
#define FE 41
#define S2CAP 192

typedef unsigned short u16;
typedef short bf16x8 __attribute__((ext_vector_type(8)));
typedef float f32x4 __attribute__((ext_vector_type(4)));

__device__ __forceinline__ float sigmoidf_(float x){ return 1.f/(1.f+expf(-x)); }

__device__ __forceinline__ u16 f2bf(float v){
  union { float f; unsigned u; } x; x.f = v;
  unsigned r = x.u + 0x7fff + ((x.u >> 16) & 1);
  return (u16)(r >> 16);
}
__device__ __forceinline__ float bf2f(u16 v){
  union { float f; unsigned u; } x; x.u = ((unsigned)v) << 16;
  return x.f;
}
__device__ __forceinline__ void split_bf(float v, u16& h, u16& l){
  h = f2bf(v); l = f2bf(v - bf2f(h));
}

// ---------------- pack/transpose small weights ----------------
__global__ void k_pack(const float* __restrict__ lin0_w, const float* __restrict__ nn1_w,
                       const float* __restrict__ root_w, const float* __restrict__ gwih,
                       const float* __restrict__ gwhh, const float* __restrict__ lwih,
                       const float* __restrict__ lwhh, const float* __restrict__ lin1_w,
                       float* __restrict__ lin0T, float* __restrict__ nn1T,
                       float* __restrict__ rootT, float* __restrict__ wihT,
                       float* __restrict__ whhT, float* __restrict__ lwihT,
                       float* __restrict__ lwhhT, float* __restrict__ lin1T)
{
  int idx = blockIdx.x*blockDim.x + threadIdx.x;
  if (idx < 92*64){ int k=idx/64, o=idx%64; lin0T[k*64+o] = lin0_w[o*92+k]; return; } idx -= 92*64;
  if (idx < 41*128){ int k=idx/128, h=idx%128; nn1T[k*128+h] = nn1_w[h*41+k]; return; } idx -= 41*128;
  if (idx < 64*64){ int i=idx/64, o=idx%64; rootT[i*64+o] = root_w[o*64+i]; return; } idx -= 64*64;
  if (idx < 64*192){ int i=idx/192, g=idx%192; wihT[i*192+g] = gwih[g*64+i]; return; } idx -= 64*192;
  if (idx < 64*192){ int i=idx/192, g=idx%192; whhT[i*192+g] = gwhh[g*64+i]; return; } idx -= 64*192;
  if (idx < 128*256){ int j=idx/256, t=idx%256; lwihT[j*256+t] = lwih[t*128+j]; return; } idx -= 128*256;
  if (idx < 64*256){ int j=idx/256, t=idx%256; lwhhT[j*256+t] = lwhh[t*64+j]; return; } idx -= 64*256;
  if (idx < 128*64){ int j=idx/64, t=idx%64; lin1T[j*64+t] = lin1_w[t*128+j]; return; }
}

// Split nn2_w into bf16 hi/lo, transposed for MFMA B-fragments:
// BT[c*262144 + (h*64+o)*64 + i] = nn2_w[(i*64+o)*128 + c*64 + h]   (c = 64-h chunk)
__global__ void k_pack_b2(const float* __restrict__ nn2_w,
                          u16* __restrict__ BhT, u16* __restrict__ BlT){
  int idx = blockIdx.x*256 + threadIdx.x;
  if (idx >= 524288) return;
  int i  = idx & 63;
  int ho = (idx >> 6) & 4095;
  int c  = idx >> 18;
  int h = ho >> 6, o = ho & 63;
  float v = nn2_w[(size_t)(i*64+o)*128 + c*64 + h];
  u16 hi, lo; split_bf(v, hi, lo);
  BhT[idx] = hi; BlT[idx] = lo;
}

// nn1_w [128,41] -> B-fragment layout [h][k] padded K=64, bf16 hi/lo
__global__ void k_pack_b1(const float* __restrict__ nn1_w,
                          u16* __restrict__ BT1h, u16* __restrict__ BT1l){
  int idx = blockIdx.x*256 + threadIdx.x;
  if (idx >= 8192) return;
  int h = idx >> 6, k = idx & 63;
  float v = (k < FE) ? nn1_w[(size_t)h*FE + k] : 0.f;
  u16 hi, lo; split_bf(v, hi, lo);
  BT1h[idx] = hi; BT1l[idx] = lo;
}

// gather ea rows into sorted order, split bf16 hi/lo, pad K 41->64
__global__ void k_split_ea(const float* __restrict__ ea, const int* __restrict__ sortedE,
                           u16* __restrict__ eaH, u16* __restrict__ eaL, int E){
  int idx = blockIdx.x*256 + threadIdx.x;
  if (idx >= E*64) return;
  int ew = idx >> 6, k = idx & 63;
  int e = sortedE[ew];
  float v = (k < FE) ? ea[(size_t)e*FE + k] : 0.f;
  u16 hi, lo; split_bf(v, hi, lo);
  eaH[idx] = hi; eaL[idx] = lo;
}

// ---------------- node MLP + bf16 shadow + fused bterm ----------------
__global__ __launch_bounds__(256) void k_node_mlp(const float* __restrict__ x,
    const float* __restrict__ lin0T, const float* __restrict__ lin0_b,
    const float* __restrict__ nn2_b,
    float* __restrict__ out, u16* __restrict__ outH, u16* __restrict__ outL,
    float* __restrict__ bterm, int N)
{
  __shared__ float xs[4][FN];
  int base = blockIdx.x*4;
  for (int i=threadIdx.x; i<4*FN; i+=256){
    int n = base + i/FN;
    xs[i/FN][i%FN] = (n<N) ? x[(size_t)n*FN + i%FN] : 0.f;
  }
  __syncthreads();
  int ln = threadIdx.x>>6, o = threadIdx.x&63;
  int n = base+ln;
  if (n>=N) return;
  float acc = lin0_b[o];
  #pragma unroll 4
  for (int k=0;k<FN;k++) acc = fmaf(xs[ln][k], lin0T[k*64+o], acc);
  float v = fmaxf(acc, 0.f);
  out[(size_t)n*64+o] = v;
  u16 hi, lo; split_bf(v, hi, lo);
  outH[(size_t)n*64+o] = hi;
  outL[(size_t)n*64+o] = lo;
  float bt = 0.f;
  #pragma unroll 8
  for (int i=0;i<64;i++) bt = fmaf(__shfl(v, i, 64), nn2_b[i*64+o], bt);
  bterm[(size_t)n*64+o] = bt;
}

// ---------------- degree + src histogram ----------------
__global__ void k_count(const int* __restrict__ dst, const int* __restrict__ src,
                        float* __restrict__ deg, int* __restrict__ scnt, int E){
  int e = blockIdx.x*blockDim.x + threadIdx.x;
  if (e < E){
    atomicAdd(&deg[dst[e]], 1.f);
    atomicAdd(&scnt[src[e]], 1);
  }
}

// ---------------- 3-kernel exclusive scan over scnt[N] ----------------
__global__ void k_scan1(const int* __restrict__ cnt, int* __restrict__ excl,
                        int* __restrict__ bsum, int N){
  __shared__ int buf[256];
  int i = blockIdx.x*256 + threadIdx.x;
  int v = (i<N) ? cnt[i] : 0;
  buf[threadIdx.x] = v;
  __syncthreads();
  #pragma unroll
  for (int off=1; off<256; off<<=1){
    int t = (threadIdx.x>=off) ? buf[threadIdx.x-off] : 0;
    __syncthreads();
    buf[threadIdx.x] += t;
    __syncthreads();
  }
  if (i<N) excl[i] = buf[threadIdx.x] - v;
  if (threadIdx.x==255) bsum[blockIdx.x] = buf[255];
}
__global__ void k_scan2(int* __restrict__ bsum, int nb){
  __shared__ int buf[256];
  int v = (threadIdx.x<nb) ? bsum[threadIdx.x] : 0;
  buf[threadIdx.x] = v;
  __syncthreads();
  #pragma unroll
  for (int off=1; off<256; off<<=1){
    int t = (threadIdx.x>=off) ? buf[threadIdx.x-off] : 0;
    __syncthreads();
    buf[threadIdx.x] += t;
    __syncthreads();
  }
  if (threadIdx.x<nb) bsum[threadIdx.x] = buf[threadIdx.x] - v;
}
__global__ void k_scan3(int* __restrict__ starts, int* __restrict__ cursor,
                        const int* __restrict__ bsum, int N, int E){
  int i = blockIdx.x*256 + threadIdx.x;
  if (i<N){
    int s = starts[i] + bsum[blockIdx.x];
    starts[i] = s;
    cursor[i] = s;
  }
  if (i==0) starts[N] = E;
}

// ---------------- scatter: sortedE grouped by src, + sorted src/dst arrays -------
__global__ void k_sort(const int* __restrict__ src, const int* __restrict__ dst,
                       int* __restrict__ cursor, int* __restrict__ sortedE,
                       int* __restrict__ srcS, int* __restrict__ dstS, int E){
  int e = blockIdx.x*256 + threadIdx.x;
  if (e < E){
    int s = src[e];
    int p = atomicAdd(&cursor[s], 1);
    sortedE[p] = e;
    srcS[p] = s;
    dstS[p] = dst[e];
  }
}

// ---------------- edge MLP via split-bf16 MFMA: hidden (sorted) = relu(ea@nn1^T+b) --
__global__ __launch_bounds__(256,3) void k_edge_mlp_mfma(
    const u16* __restrict__ eaH, const u16* __restrict__ eaL,
    const u16* __restrict__ BT1h, const u16* __restrict__ BT1l,
    const float* __restrict__ nn1_b, float* __restrict__ hidden, int E)
{
  const int lane = threadIdx.x & 63;
  const int wave = threadIdx.x >> 6;
  const int row  = lane & 15;
  const int quad = lane >> 4;
  const int m0 = blockIdx.x*128 + (wave>>1)*64;
  const int n0 = (wave&1)*64;

  bf16x8 AH0[4], AH1[4], AL0[4], AL1[4];
  #pragma unroll
  for (int p=0;p<4;p++){
    int ar = min(m0 + p*16 + row, E-1);
    const u16* aH = eaH + (size_t)ar*64 + quad*8;
    const u16* aL = eaL + (size_t)ar*64 + quad*8;
    AH0[p] = *(const bf16x8*)(aH);
    AH1[p] = *(const bf16x8*)(aH + 32);
    AL0[p] = *(const bf16x8*)(aL);
    AL1[p] = *(const bf16x8*)(aL + 32);
  }
  // swapped-operand form: acc[tb][ta], lane holds row m = m0+ta*16+(lane&15),
  // cols n = n0+tb*16+quad*4 .. +3  -> direct float4 store.
  #pragma unroll
  for (int tb=0;tb<4;tb++){
    const u16* bH = BT1h + (size_t)(n0 + tb*16 + row)*64 + quad*8;
    const u16* bL = BT1l + (size_t)(n0 + tb*16 + row)*64 + quad*8;
    bf16x8 bh0 = *(const bf16x8*)(bH);
    bf16x8 bh1 = *(const bf16x8*)(bH + 32);
    bf16x8 bl0 = *(const bf16x8*)(bL);
    bf16x8 bl1 = *(const bf16x8*)(bL + 32);
    float4 bias;
    {
      int nb = n0 + tb*16 + quad*4;
      bias.x = nn1_b[nb+0]; bias.y = nn1_b[nb+1];
      bias.z = nn1_b[nb+2]; bias.w = nn1_b[nb+3];
    }
    #pragma unroll
    for (int ta=0;ta<4;ta++){
      f32x4 a = {0.f,0.f,0.f,0.f};
      a = __builtin_amdgcn_mfma_f32_16x16x32_bf16(bh0, AH0[ta], a, 0,0,0);
      a = __builtin_amdgcn_mfma_f32_16x16x32_bf16(bh1, AH1[ta], a, 0,0,0);
      a = __builtin_amdgcn_mfma_f32_16x16x32_bf16(bl0, AH0[ta], a, 0,0,0);
      a = __builtin_amdgcn_mfma_f32_16x16x32_bf16(bl1, AH1[ta], a, 0,0,0);
      a = __builtin_amdgcn_mfma_f32_16x16x32_bf16(bh0, AL0[ta], a, 0,0,0);
      a = __builtin_amdgcn_mfma_f32_16x16x32_bf16(bh1, AL1[ta], a, 0,0,0);
      int m = m0 + ta*16 + row;
      if (m < E){
        float4 v;
        v.x = fmaxf(a[0]+bias.x, 0.f); v.y = fmaxf(a[1]+bias.y, 0.f);
        v.z = fmaxf(a[2]+bias.z, 0.f); v.w = fmaxf(a[3]+bias.w, 0.f);
        *(float4*)(hidden + (size_t)m*128 + n0 + tb*16 + quad*4) = v;
      }
    }
  }
}

// ---------------- Q GEMM via split-bf16 MFMA, swapped operands, direct stores -----
__global__ __launch_bounds__(256,3) void k_qgemm_mfma(
    const u16* __restrict__ Ah, const u16* __restrict__ Al,
    const u16* __restrict__ BhT, const u16* __restrict__ BlT,
    float* __restrict__ C, int M)
{
  const int lane = threadIdx.x & 63;
  const int wave = threadIdx.x >> 6;
  const int row  = lane & 15;
  const int quad = lane >> 4;
  const int m0 = blockIdx.y * 64;
  const int n0 = blockIdx.x * 256 + wave * 64;

  bf16x8 AH0[4], AH1[4], AL0[4], AL1[4];
  #pragma unroll
  for (int p=0;p<4;p++){
    int ar = min(m0 + p*16 + row, M-1);
    const u16* aH = Ah + (size_t)ar*64 + quad*8;
    const u16* aL = Al + (size_t)ar*64 + quad*8;
    AH0[p] = *(const bf16x8*)(aH);
    AH1[p] = *(const bf16x8*)(aH + 32);
    AL0[p] = *(const bf16x8*)(aL);
    AL1[p] = *(const bf16x8*)(aL + 32);
  }

  #pragma unroll
  for (int tb=0;tb<4;tb++){
    const u16* bH = BhT + (size_t)(n0 + tb*16 + row)*64 + quad*8;
    const u16* bL = BlT + (size_t)(n0 + tb*16 + row)*64 + quad*8;
    bf16x8 bh0 = *(const bf16x8*)(bH);
    bf16x8 bh1 = *(const bf16x8*)(bH + 32);
    bf16x8 bl0 = *(const bf16x8*)(bL);
    bf16x8 bl1 = *(const bf16x8*)(bL + 32);
    #pragma unroll
    for (int ta=0;ta<4;ta++){
      f32x4 a = {0.f,0.f,0.f,0.f};
      a = __builtin_amdgcn_mfma_f32_16x16x32_bf16(bh0, AH0[ta], a, 0,0,0);
      a = __builtin_amdgcn_mfma_f32_16x16x32_bf16(bh1, AH1[ta], a, 0,0,0);
      a = __builtin_amdgcn_mfma_f32_16x16x32_bf16(bl0, AH0[ta], a, 0,0,0);
      a = __builtin_amdgcn_mfma_f32_16x16x32_bf16(bl1, AH1[ta], a, 0,0,0);
      a = __builtin_amdgcn_mfma_f32_16x16x32_bf16(bh0, AL0[ta], a, 0,0,0);
      a = __builtin_amdgcn_mfma_f32_16x16x32_bf16(bh1, AL1[ta], a, 0,0,0);
      int m = m0 + ta*16 + row;
      if (m < M){
        float4 v; v.x=a[0]; v.y=a[1]; v.z=a[2]; v.w=a[3];
        *(float4*)(C + (size_t)m*4096 + n0 + tb*16 + quad*4) = v;
      }
    }
  }
}

// ---------------- edge gather v3: 4 edges/wave, no barriers ----------------
template<int PASS>
__global__ __launch_bounds__(256) void k_edge_gather(const float* __restrict__ Q,
    const float* __restrict__ hidden, int h0,
    const float* __restrict__ bterm, const int* __restrict__ srcS,
    const int* __restrict__ dstS,
    float* __restrict__ msg, float* __restrict__ agg, int E)
{
  __shared__ float hs[4][4][64];
  __shared__ float red[4][4][64];
  const int wv = threadIdx.x>>6, lane = threadIdx.x&63;
  const int ewb = (blockIdx.x*4 + wv)*4;
  int ee[4]; bool vv[4]; int ss[4];
  #pragma unroll
  for (int i=0;i<4;i++){
    vv[i] = (ewb+i < E);
    ee[i] = vv[i] ? ewb+i : 0;
    ss[i] = srcS[ee[i]];
    hs[wv][i][lane] = hidden[(size_t)ee[i]*128 + h0 + lane];
  }
  // per-wave LDS only: in-wave lgkmcnt ordering suffices, no __syncthreads
  const int sg = lane>>4, oq = lane&15;
  float acc[4][4];
  #pragma unroll
  for (int i=0;i<4;i++)
    #pragma unroll
    for (int r=0;r<4;r++) acc[i][r] = 0.f;
  const float* qp[4];
  #pragma unroll
  for (int i=0;i<4;i++) qp[i] = Q + (size_t)ss[i]*4096 + sg*64 + oq*4;
  #pragma unroll
  for (int j=0;j<16;j++){
    #pragma unroll
    for (int i=0;i<4;i++){
      float4 q = *(const float4*)(qp[i] + j*256);
      float hv = hs[wv][i][j*4 + sg];
      acc[i][0] = fmaf(hv, q.x, acc[i][0]);
      acc[i][1] = fmaf(hv, q.y, acc[i][1]);
      acc[i][2] = fmaf(hv, q.z, acc[i][2]);
      acc[i][3] = fmaf(hv, q.w, acc[i][3]);
    }
  }
  #pragma unroll
  for (int i=0;i<4;i++){
    #pragma unroll
    for (int r=0;r<4;r++){
      acc[i][r] += __shfl_xor(acc[i][r],16);
      acc[i][r] += __shfl_xor(acc[i][r],32);
    }
  }
  if (lane < 16){
    #pragma unroll
    for (int i=0;i<4;i++){
      float4 r0; r0.x=acc[i][0]; r0.y=acc[i][1]; r0.z=acc[i][2]; r0.w=acc[i][3];
      *(float4*)&red[wv][i][lane*4] = r0;
    }
  }
  // in-wave lgkmcnt ordering; no barrier
  #pragma unroll
  for (int i=0;i<4;i++){
    if (vv[i]){
      float rv = red[wv][i][lane];
      int ew = ewb+i;
      if (PASS == 0) msg[(size_t)ew*64 + lane] = bterm[(size_t)ss[i]*64 + lane] + rv;
      else atomicAdd(&agg[(size_t)dstS[ew]*64 + lane], msg[(size_t)ew*64 + lane] + rv);
    }
  }
}

// ---------------- agg-normalize + root + GRU + bf16 shadow + fused bterm ---------
__global__ __launch_bounds__(256) void k_node_update(const float* __restrict__ outOld,
    const float* __restrict__ agg, const float* __restrict__ deg,
    const float* __restrict__ rootT, const float* __restrict__ conv_b,
    const float* __restrict__ wihT, const float* __restrict__ whhT,
    const float* __restrict__ b_ih, const float* __restrict__ b_hh,
    const float* __restrict__ nn2_b,
    float* __restrict__ outNew, u16* __restrict__ outH, u16* __restrict__ outL,
    float* __restrict__ bterm, int N)
{
  __shared__ float hs[4][64];
  __shared__ float ms[4][64];
  int ln = threadIdx.x>>6, o = threadIdx.x&63;
  int n = blockIdx.x*4+ln;
  bool ok = (n<N);
  float h = ok ? outOld[(size_t)n*64+o] : 0.f;
  hs[ln][o] = h;
  __syncthreads();
  float root = 0.f;
  #pragma unroll 8
  for (int i=0;i<64;i++) root = fmaf(hs[ln][i], rootT[i*64+o], root);
  float d = ok ? fmaxf(deg[n], 1.f) : 1.f;
  float a = ok ? agg[(size_t)n*64+o]/d : 0.f;
  float m = fmaxf(a + root + conv_b[o], 0.f);
  ms[ln][o] = m;
  __syncthreads();
  float gir=b_ih[o], giz=b_ih[64+o], gin=b_ih[128+o];
  float ghr=b_hh[o], ghz=b_hh[64+o], ghn=b_hh[128+o];
  #pragma unroll 4
  for (int i=0;i<64;i++){
    float mi = ms[ln][i], hi = hs[ln][i];
    gir = fmaf(mi, wihT[i*192+o],      gir);
    giz = fmaf(mi, wihT[i*192+64+o],   giz);
    gin = fmaf(mi, wihT[i*192+128+o],  gin);
    ghr = fmaf(hi, whhT[i*192+o],      ghr);
    ghz = fmaf(hi, whhT[i*192+64+o],   ghz);
    ghn = fmaf(hi, whhT[i*192+128+o],  ghn);
  }
  float r = sigmoidf_(gir+ghr);
  float z = sigmoidf_(giz+ghz);
  float nn = tanhf(gin + r*ghn);
  if (ok){
    float v = (1.f-z)*nn + z*h;
    outNew[(size_t)n*64+o] = v;
    u16 hi16, lo16; split_bf(v, hi16, lo16);
    outH[(size_t)n*64+o] = hi16;
    outL[(size_t)n*64+o] = lo16;
    float bt = 0.f;
    #pragma unroll 8
    for (int i=0;i<64;i++) bt = fmaf(__shfl(v, i, 64), nn2_b[i*64+o], bt);
    bterm[(size_t)n*64+o] = bt;
  }
}

// ---------------- Set2Set (3 steps) + final MLP: LDS-staged, one block/graph -------
__global__ __launch_bounds__(256) void k_set2set(const float* __restrict__ out,
    const int* __restrict__ batch, int N,
    const float* __restrict__ lwihT, const float* __restrict__ lwhhT,
    const float* __restrict__ b_ih, const float* __restrict__ b_hh,
    const float* __restrict__ lin1T, const float* __restrict__ lin1_b,
    const float* __restrict__ lin2_w, const float* __restrict__ lin2_b,
    float* __restrict__ y)
{
  __shared__ float X[S2CAP][65];
  __shared__ float earr[S2CAP];
  __shared__ float qstar[128], hl[64], cl[64], g[256];
  __shared__ float rpart[4][64], spart[4], redm[4], zs[64];
  __shared__ int sb[2];
  const int tid = threadIdx.x;
  const int b = blockIdx.x;
  const int wid = tid>>6, lane = tid&63;
  if (tid < 128) qstar[tid] = 0.f;
  if (tid < 64){ hl[tid]=0.f; cl[tid]=0.f; }
  if (tid == 0){
    int lo=0, hi=N;
    while (lo<hi){ int mid=(lo+hi)>>1; if (batch[mid] < b) lo=mid+1; else hi=mid; }
    sb[0]=lo;
    int lo2=lo, hi2=N;
    while (lo2<hi2){ int mid=(lo2+hi2)>>1; if (batch[mid] < b+1) lo2=mid+1; else hi2=mid; }
    sb[1]=lo2;
  }
  __syncthreads();
  const int nlo = sb[0], nhi = sb[1], nn = nhi - nlo;
  const bool single = (nn <= S2CAP);
  if (single){
    for (int idx = tid; idx < nn*64; idx += 256){
      X[idx>>6][idx&63] = out[(size_t)(nlo + (idx>>6))*64 + (idx&63)];
    }
  }
  __syncthreads();

  for (int step=0; step<3; step++){
    float gs = b_ih[tid] + b_hh[tid];
    for (int j=0;j<128;j++) gs = fmaf(qstar[j], lwihT[j*256+tid], gs);
    for (int j=0;j<64;j++)  gs = fmaf(hl[j],    lwhhT[j*256+tid], gs);
    g[tid] = gs;
    __syncthreads();
    if (tid < 64){
      float ig = sigmoidf_(g[tid]);
      float fg = sigmoidf_(g[64+tid]);
      float gg = tanhf(g[128+tid]);
      float og = sigmoidf_(g[192+tid]);
      float c = fg*cl[tid] + ig*gg;
      cl[tid] = c;
      hl[tid] = og*tanhf(c);
    }
    __syncthreads();

    if (single){
      float lm = -INFINITY;
      for (int n = tid; n < nn; n += 256){
        float acc = 0.f;
        #pragma unroll 8
        for (int d=0; d<64; d++) acc = fmaf(X[n][d], hl[d], acc);
        earr[n] = acc;
        lm = fmaxf(lm, acc);
      }
      lm = fmaxf(lm, __shfl_xor(lm,1));  lm = fmaxf(lm, __shfl_xor(lm,2));
      lm = fmaxf(lm, __shfl_xor(lm,4));  lm = fmaxf(lm, __shfl_xor(lm,8));
      lm = fmaxf(lm, __shfl_xor(lm,16)); lm = fmaxf(lm, __shfl_xor(lm,32));
      if (lane==0) redm[wid] = lm;
      __syncthreads();
      if (tid==0) redm[0] = fmaxf(fmaxf(redm[0],redm[1]), fmaxf(redm[2],redm[3]));
      __syncthreads();
      const float gmax = redm[0];
      float ls = 0.f;
      for (int n = tid; n < nn; n += 256){
        float a = expf(earr[n] - gmax);
        earr[n] = a;
        ls += a;
      }
      ls += __shfl_xor(ls,1);  ls += __shfl_xor(ls,2);  ls += __shfl_xor(ls,4);
      ls += __shfl_xor(ls,8);  ls += __shfl_xor(ls,16); ls += __shfl_xor(ls,32);
      if (lane==0) spart[wid] = ls;
      __syncthreads();
      float racc = 0.f;
      for (int n = wid; n < nn; n += 4) racc = fmaf(earr[n], X[n][lane], racc);
      rpart[wid][lane] = racc;
      __syncthreads();
      if (tid < 64){
        float r = rpart[0][tid]+rpart[1][tid]+rpart[2][tid]+rpart[3][tid];
        float s = spart[0]+spart[1]+spart[2]+spart[3];
        qstar[tid] = hl[tid];
        qstar[64+tid] = (nn>0) ? r/s : 0.f;
      }
      __syncthreads();
    } else {
      float qv = hl[lane];
      float lm = -INFINITY;
      for (int n = nlo + wid; n < nhi; n += 4){
        float p = out[(size_t)n*64 + lane]*qv;
        p += __shfl_xor(p,1); p += __shfl_xor(p,2); p += __shfl_xor(p,4);
        p += __shfl_xor(p,8); p += __shfl_xor(p,16); p += __shfl_xor(p,32);
        lm = fmaxf(lm, p);
      }
      if (lane==0) redm[wid] = lm;
      __syncthreads();
      if (tid==0) redm[0] = fmaxf(fmaxf(redm[0],redm[1]), fmaxf(redm[2],redm[3]));
      __syncthreads();
      float gmax = redm[0];
      float sw = 0.f, racc = 0.f;
      for (int n = nlo + wid; n < nhi; n += 4){
        float ol = out[(size_t)n*64 + lane];
        float p = ol*qv;
        p += __shfl_xor(p,1); p += __shfl_xor(p,2); p += __shfl_xor(p,4);
        p += __shfl_xor(p,8); p += __shfl_xor(p,16); p += __shfl_xor(p,32);
        float a = expf(p - gmax);
        sw += a;
        racc = fmaf(a, ol, racc);
      }
      rpart[wid][lane] = racc;
      if (lane==0) spart[wid] = sw;
      __syncthreads();
      if (tid < 64){
        float r = rpart[0][tid]+rpart[1][tid]+rpart[2][tid]+rpart[3][tid];
        float s = spart[0]+spart[1]+spart[2]+spart[3];
        qstar[tid] = hl[tid];
        qstar[64+tid] = (nn>0) ? r/s : 0.f;
      }
      __syncthreads();
    }
  }
  if (tid < 64){
    float acc = lin1_b[tid];
    for (int j=0;j<128;j++) acc = fmaf(qstar[j], lin1T[j*64+tid], acc);
    zs[tid] = fmaxf(acc, 0.f);
  }
  __syncthreads();
  if (tid < 64){
    float v = zs[lane]*lin2_w[lane];
    v += __shfl_xor(v,1); v += __shfl_xor(v,2); v += __shfl_xor(v,4);
    v += __shfl_xor(v,8); v += __shfl_xor(v,16); v += __shfl_xor(v,32);
    if (lane==0) y[b] = v + lin2_b[0];
  }
}

extern "C" void kernel_launch(void* const* d_in, const int* in_sizes, int n_in,
                              void* d_out, int out_size, void* d_ws, size_t ws_size,
                              hipStream_t stream)
{
  const float* x      = (const float*)d_in[0];
  const float* eattr  = (const float*)d_in[1];
  const float* lin0_w = (const float*)d_in[2];
  const float* lin0_b = (const float*)d_in[3];
  const float* nn1_w  = (const float*)d_in[4];
  const float* nn1_b  = (const float*)d_in[5];
  const float* nn2_w  = (const float*)d_in[6];
  const float* nn2_b  = (const float*)d_in[7];
  const float* root_w = (const float*)d_in[8];
  const float* conv_b = (const float*)d_in[9];
  const float* gwih   = (const float*)d_in[10];
  const float* gwhh   = (const float*)d_in[11];
  const float* gbih   = (const float*)d_in[12];
  const float* gbhh   = (const float*)d_in[13];
  const float* lwih   = (const float*)d_in[14];
  const float* lwhh   = (const float*)d_in[15];
  const float* lbih   = (const float*)d_in[16];
  const float* lbhh   = (const float*)d_in[17];
  const float* lin1_w = (const float*)d_in[18];
  const float* lin1_b = (const float*)d_in[19];
  const float* lin2_w = (const float*)d_in[20];
  const float* lin2_b = (const float*)d_in[21];
  const int*   eidx   = (const int*)d_in[22];
  const int*   batch  = (const int*)d_in[23];

  const int N = in_sizes[0]/FN;
  const int E = in_sizes[1]/FE;
  const int* srcI = eidx;
  const int* dstI = eidx + E;

  char* w = (char*)d_ws;
  size_t off = 0;
  auto alloc = [&](size_t bytes)->char* {
    char* p = w + off;
    off = (off + bytes + 255) & ~(size_t)255;
    return p;
  };
  float* degw  = (float*)alloc((size_t)N*4);
  int*   scnt  = (int*)alloc((size_t)N*4);
  int*   starts= (int*)alloc((size_t)(N+1)*4);
  int*   cursor= (int*)alloc((size_t)N*4);
  int*   bsum  = (int*)alloc((size_t)256*4);
  int*   sortedE=(int*)alloc((size_t)E*4);
  int*   srcS  = (int*)alloc((size_t)E*4);
  int*   dstS  = (int*)alloc((size_t)E*4);
  float* outA  = (float*)alloc((size_t)N*64*4);
  float* outB  = (float*)alloc((size_t)N*64*4);
  u16*   outAH = (u16*)alloc((size_t)N*64*2);
  u16*   outAL = (u16*)alloc((size_t)N*64*2);
  u16*   outBH = (u16*)alloc((size_t)N*64*2);
  u16*   outBL = (u16*)alloc((size_t)N*64*2);
  float* agg   = (float*)alloc((size_t)N*64*4);
  float* bterm = (float*)alloc((size_t)N*64*4);
  float* hidden= (float*)alloc((size_t)E*128*4);
  float* msg   = (float*)alloc((size_t)E*64*4);
  u16*   B2hT  = (u16*)alloc((size_t)524288*2);
  u16*   B2lT  = (u16*)alloc((size_t)524288*2);
  u16*   BT1h  = (u16*)alloc((size_t)8192*2);
  u16*   BT1l  = (u16*)alloc((size_t)8192*2);
  float* lin0T = (float*)alloc((size_t)92*64*4);
  float* nn1T  = (float*)alloc((size_t)41*128*4);
  float* rootT = (float*)alloc((size_t)64*64*4);
  float* wihT  = (float*)alloc((size_t)64*192*4);
  float* whhT  = (float*)alloc((size_t)64*192*4);
  float* lwihT = (float*)alloc((size_t)128*256*4);
  float* lwhhT = (float*)alloc((size_t)64*256*4);
  float* lin1T = (float*)alloc((size_t)128*64*4);
  float* Q     = (float*)alloc((size_t)N*4096*4);   // one 64-h chunk: [n][h*64+o]
  // eaH/eaL overlay Q's buffer: consumed by k_edge_mlp_mfma before first qgemm write
  u16* eaH = (u16*)Q;
  u16* eaL = eaH + (size_t)E*64;

  const int NB = (N+255)/256;

  hipMemsetAsync(degw, 0, (size_t)N*4, stream);
  hipMemsetAsync(scnt, 0, (size_t)N*4, stream);
  k_pack<<<(97152+255)/256, 256, 0, stream>>>(lin0_w, nn1_w, root_w, gwih, gwhh,
      lwih, lwhh, lin1_w, lin0T, nn1T, rootT, wihT, whhT, lwihT, lwhhT, lin1T);
  k_pack_b2<<<524288/256, 256, 0, stream>>>(nn2_w, B2hT, B2lT);
  k_pack_b1<<<8192/256, 256, 0, stream>>>(nn1_w, BT1h, BT1l);
  k_node_mlp<<<(N+3)/4, 256, 0, stream>>>(x, lin0T, lin0_b, nn2_b, outA, outAH, outAL, bterm, N);
  k_count<<<(E+255)/256, 256, 0, stream>>>(dstI, srcI, degw, scnt, E);
  k_scan1<<<NB, 256, 0, stream>>>(scnt, starts, bsum, N);
  k_scan2<<<1, 256, 0, stream>>>(bsum, NB);
  k_scan3<<<NB, 256, 0, stream>>>(starts, cursor, bsum, N, E);
  k_sort<<<(E+255)/256, 256, 0, stream>>>(srcI, dstI, cursor, sortedE, srcS, dstS, E);
  k_split_ea<<<((size_t)E*64+255)/256, 256, 0, stream>>>(eattr, sortedE, eaH, eaL, E);
  k_edge_mlp_mfma<<<(E+127)/128, 256, 0, stream>>>(eaH, eaL, BT1h, BT1l, nn1_b, hidden, E);

  float* cur = outA; float* nxt = outB;
  u16* curH = outAH; u16* curL = outAL;
  u16* nxtH = outBH; u16* nxtL = outBL;
  const dim3 qgrid(16, (N+63)/64);
  const int gatherGx = (E+15)/16;
  for (int conv=0; conv<2; conv++){
    hipMemsetAsync(agg, 0, (size_t)N*64*4, stream);
    // chunk 0 (h in [0,64))
    k_qgemm_mfma<<<qgrid, 256, 0, stream>>>(curH, curL, B2hT, B2lT, Q, N);
    k_edge_gather<0><<<gatherGx, 256, 0, stream>>>(Q, hidden, 0, bterm, srcS, dstS, msg, agg, E);
    // chunk 1 (h in [64,128))
    k_qgemm_mfma<<<qgrid, 256, 0, stream>>>(curH, curL, B2hT + 262144, B2lT + 262144, Q, N);
    k_edge_gather<1><<<gatherGx, 256, 0, stream>>>(Q, hidden, 64, bterm, srcS, dstS, msg, agg, E);
    k_node_update<<<(N+3)/4, 256, 0, stream>>>(cur, agg, degw, rootT, conv_b,
        wihT, whhT, gbih, gbhh, nn2_b, nxt, nxtH, nxtL, bterm, N);
    float* t = cur; cur = nxt; nxt = t;
    u16* th = curH; curH = nxtH; nxtH = th;
    u16* tl = curL; curL = nxtL; nxtL = tl;
  }

  k_set2set<<<128, 256, 0, stream>>>(cur, batch, N, lwihT, lwhhT, lbih, lbhh,
      lin1T, lin1_b, lin2_w, lin2_b, (float*)d_out);
}

// Round 14
// 678.066 us; speedup vs baseline: 1.0614x; 1.0614x over previous
//
#include <hip/hip_runtime.h>
#include <hip/hip_bf16.h>
#include <math.h>

#define DD 64
#define HIDC 128
#define FN 92
#define FE 41
#define S2CAP 192

typedef unsigned short u16;
typedef short bf16x8 __attribute__((ext_vector_type(8)));
typedef float f32x4 __attribute__((ext_vector_type(4)));

__device__ __forceinline__ float sigmoidf_(float x){ return 1.f/(1.f+expf(-x)); }

__device__ __forceinline__ u16 f2bf(float v){
  union { float f; unsigned u; } x; x.f = v;
  unsigned r = x.u + 0x7fff + ((x.u >> 16) & 1);
  return (u16)(r >> 16);
}
__device__ __forceinline__ float bf2f(u16 v){
  union { float f; unsigned u; } x; x.u = ((unsigned)v) << 16;
  return x.f;
}
__device__ __forceinline__ void split_bf(float v, u16& h, u16& l){
  h = f2bf(v); l = f2bf(v - bf2f(h));
}

// ---------------- pack/transpose small weights ----------------
__global__ void k_pack(const float* __restrict__ lin0_w, const float* __restrict__ nn1_w,
                       const float* __restrict__ root_w, const float* __restrict__ gwih,
                       const float* __restrict__ gwhh, const float* __restrict__ lwih,
                       const float* __restrict__ lwhh, const float* __restrict__ lin1_w,
                       float* __restrict__ lin0T, float* __restrict__ nn1T,
                       float* __restrict__ rootT, float* __restrict__ wihT,
                       float* __restrict__ whhT, float* __restrict__ lwihT,
                       float* __restrict__ lwhhT, float* __restrict__ lin1T)
{
  int idx = blockIdx.x*blockDim.x + threadIdx.x;
  if (idx < 92*64){ int k=idx/64, o=idx%64; lin0T[k*64+o] = lin0_w[o*92+k]; return; } idx -= 92*64;
  if (idx < 41*128){ int k=idx/128, h=idx%128; nn1T[k*128+h] = nn1_w[h*41+k]; return; } idx -= 41*128;
  if (idx < 64*64){ int i=idx/64, o=idx%64; rootT[i*64+o] = root_w[o*64+i]; return; } idx -= 64*64;
  if (idx < 64*192){ int i=idx/192, g=idx%192; wihT[i*192+g] = gwih[g*64+i]; return; } idx -= 64*192;
  if (idx < 64*192){ int i=idx/192, g=idx%192; whhT[i*192+g] = gwhh[g*64+i]; return; } idx -= 64*192;
  if (idx < 128*256){ int j=idx/256, t=idx%256; lwihT[j*256+t] = lwih[t*128+j]; return; } idx -= 128*256;
  if (idx < 64*256){ int j=idx/256, t=idx%256; lwhhT[j*256+t] = lwhh[t*64+j]; return; } idx -= 64*256;
  if (idx < 128*64){ int j=idx/64, t=idx%64; lin1T[j*64+t] = lin1_w[t*128+j]; return; }
}

// Split nn2_w into bf16 hi/lo, transposed for MFMA B-fragments:
// BT[c*262144 + (h*64+o)*64 + i] = nn2_w[(i*64+o)*128 + c*64 + h]   (c = 64-h chunk)
__global__ void k_pack_b2(const float* __restrict__ nn2_w,
                          u16* __restrict__ BhT, u16* __restrict__ BlT){
  int idx = blockIdx.x*256 + threadIdx.x;
  if (idx >= 524288) return;
  int i  = idx & 63;
  int ho = (idx >> 6) & 4095;
  int c  = idx >> 18;
  int h = ho >> 6, o = ho & 63;
  float v = nn2_w[(size_t)(i*64+o)*128 + c*64 + h];
  u16 hi, lo; split_bf(v, hi, lo);
  BhT[idx] = hi; BlT[idx] = lo;
}

// nn1_w [128,41] -> B-fragment layout [h][k] padded K=64, bf16 hi/lo
__global__ void k_pack_b1(const float* __restrict__ nn1_w,
                          u16* __restrict__ BT1h, u16* __restrict__ BT1l){
  int idx = blockIdx.x*256 + threadIdx.x;
  if (idx >= 8192) return;
  int h = idx >> 6, k = idx & 63;
  float v = (k < FE) ? nn1_w[(size_t)h*FE + k] : 0.f;
  u16 hi, lo; split_bf(v, hi, lo);
  BT1h[idx] = hi; BT1l[idx] = lo;
}

// gather ea rows into sorted order, split bf16 hi/lo, pad K 41->64
__global__ void k_split_ea(const float* __restrict__ ea, const int* __restrict__ sortedE,
                           u16* __restrict__ eaH, u16* __restrict__ eaL, int E){
  int idx = blockIdx.x*256 + threadIdx.x;
  if (idx >= E*64) return;
  int ew = idx >> 6, k = idx & 63;
  int e = sortedE[ew];
  float v = (k < FE) ? ea[(size_t)e*FE + k] : 0.f;
  u16 hi, lo; split_bf(v, hi, lo);
  eaH[idx] = hi; eaL[idx] = lo;
}

// ---------------- node MLP + bf16 shadow + fused bterm ----------------
__global__ __launch_bounds__(256) void k_node_mlp(const float* __restrict__ x,
    const float* __restrict__ lin0T, const float* __restrict__ lin0_b,
    const float* __restrict__ nn2_b,
    float* __restrict__ out, u16* __restrict__ outH, u16* __restrict__ outL,
    float* __restrict__ bterm, int N)
{
  __shared__ float xs[4][FN];
  int base = blockIdx.x*4;
  for (int i=threadIdx.x; i<4*FN; i+=256){
    int n = base + i/FN;
    xs[i/FN][i%FN] = (n<N) ? x[(size_t)n*FN + i%FN] : 0.f;
  }
  __syncthreads();
  int ln = threadIdx.x>>6, o = threadIdx.x&63;
  int n = base+ln;
  if (n>=N) return;
  float acc = lin0_b[o];
  #pragma unroll 4
  for (int k=0;k<FN;k++) acc = fmaf(xs[ln][k], lin0T[k*64+o], acc);
  float v = fmaxf(acc, 0.f);
  out[(size_t)n*64+o] = v;
  u16 hi, lo; split_bf(v, hi, lo);
  outH[(size_t)n*64+o] = hi;
  outL[(size_t)n*64+o] = lo;
  float bt = 0.f;
  #pragma unroll 8
  for (int i=0;i<64;i++) bt = fmaf(__shfl(v, i, 64), nn2_b[i*64+o], bt);
  bterm[(size_t)n*64+o] = bt;
}

// ---------------- degree + src histogram ----------------
__global__ void k_count(const int* __restrict__ dst, const int* __restrict__ src,
                        float* __restrict__ deg, int* __restrict__ scnt, int E){
  int e = blockIdx.x*blockDim.x + threadIdx.x;
  if (e < E){
    atomicAdd(&deg[dst[e]], 1.f);
    atomicAdd(&scnt[src[e]], 1);
  }
}

// ---------------- 3-kernel exclusive scan over scnt[N] ----------------
__global__ void k_scan1(const int* __restrict__ cnt, int* __restrict__ excl,
                        int* __restrict__ bsum, int N){
  __shared__ int buf[256];
  int i = blockIdx.x*256 + threadIdx.x;
  int v = (i<N) ? cnt[i] : 0;
  buf[threadIdx.x] = v;
  __syncthreads();
  #pragma unroll
  for (int off=1; off<256; off<<=1){
    int t = (threadIdx.x>=off) ? buf[threadIdx.x-off] : 0;
    __syncthreads();
    buf[threadIdx.x] += t;
    __syncthreads();
  }
  if (i<N) excl[i] = buf[threadIdx.x] - v;
  if (threadIdx.x==255) bsum[blockIdx.x] = buf[255];
}
__global__ void k_scan2(int* __restrict__ bsum, int nb){
  __shared__ int buf[256];
  int v = (threadIdx.x<nb) ? bsum[threadIdx.x] : 0;
  buf[threadIdx.x] = v;
  __syncthreads();
  #pragma unroll
  for (int off=1; off<256; off<<=1){
    int t = (threadIdx.x>=off) ? buf[threadIdx.x-off] : 0;
    __syncthreads();
    buf[threadIdx.x] += t;
    __syncthreads();
  }
  if (threadIdx.x<nb) bsum[threadIdx.x] = buf[threadIdx.x] - v;
}
__global__ void k_scan3(int* __restrict__ starts, int* __restrict__ cursor,
                        const int* __restrict__ bsum, int N, int E){
  int i = blockIdx.x*256 + threadIdx.x;
  if (i<N){
    int s = starts[i] + bsum[blockIdx.x];
    starts[i] = s;
    cursor[i] = s;
  }
  if (i==0) starts[N] = E;
}

// ---------------- scatter: sortedE grouped by src, + sorted src/dst arrays -------
__global__ void k_sort(const int* __restrict__ src, const int* __restrict__ dst,
                       int* __restrict__ cursor, int* __restrict__ sortedE,
                       int* __restrict__ srcS, int* __restrict__ dstS, int E){
  int e = blockIdx.x*256 + threadIdx.x;
  if (e < E){
    int s = src[e];
    int p = atomicAdd(&cursor[s], 1);
    sortedE[p] = e;
    srcS[p] = s;
    dstS[p] = dst[e];
  }
}

// ---------------- edge MLP via split-bf16 MFMA, swapped operands, direct stores ----
__global__ __launch_bounds__(256,3) void k_edge_mlp_mfma(
    const u16* __restrict__ eaH, const u16* __restrict__ eaL,
    const u16* __restrict__ BT1h, const u16* __restrict__ BT1l,
    const float* __restrict__ nn1_b, float* __restrict__ hidden, int E)
{
  const int lane = threadIdx.x & 63;
  const int wave = threadIdx.x >> 6;
  const int row  = lane & 15;
  const int quad = lane >> 4;
  const int m0 = blockIdx.x*128 + (wave>>1)*64;
  const int n0 = (wave&1)*64;

  bf16x8 AH0[4], AH1[4], AL0[4], AL1[4];
  #pragma unroll
  for (int p=0;p<4;p++){
    int ar = min(m0 + p*16 + row, E-1);
    const u16* aH = eaH + (size_t)ar*64 + quad*8;
    const u16* aL = eaL + (size_t)ar*64 + quad*8;
    AH0[p] = *(const bf16x8*)(aH);
    AH1[p] = *(const bf16x8*)(aH + 32);
    AL0[p] = *(const bf16x8*)(aL);
    AL1[p] = *(const bf16x8*)(aL + 32);
  }
  #pragma unroll
  for (int tb=0;tb<4;tb++){
    const u16* bH = BT1h + (size_t)(n0 + tb*16 + row)*64 + quad*8;
    const u16* bL = BT1l + (size_t)(n0 + tb*16 + row)*64 + quad*8;
    bf16x8 bh0 = *(const bf16x8*)(bH);
    bf16x8 bh1 = *(const bf16x8*)(bH + 32);
    bf16x8 bl0 = *(const bf16x8*)(bL);
    bf16x8 bl1 = *(const bf16x8*)(bL + 32);
    float4 bias;
    {
      int nb = n0 + tb*16 + quad*4;
      bias.x = nn1_b[nb+0]; bias.y = nn1_b[nb+1];
      bias.z = nn1_b[nb+2]; bias.w = nn1_b[nb+3];
    }
    #pragma unroll
    for (int ta=0;ta<4;ta++){
      f32x4 a = {0.f,0.f,0.f,0.f};
      a = __builtin_amdgcn_mfma_f32_16x16x32_bf16(bh0, AH0[ta], a, 0,0,0);
      a = __builtin_amdgcn_mfma_f32_16x16x32_bf16(bh1, AH1[ta], a, 0,0,0);
      a = __builtin_amdgcn_mfma_f32_16x16x32_bf16(bl0, AH0[ta], a, 0,0,0);
      a = __builtin_amdgcn_mfma_f32_16x16x32_bf16(bl1, AH1[ta], a, 0,0,0);
      a = __builtin_amdgcn_mfma_f32_16x16x32_bf16(bh0, AL0[ta], a, 0,0,0);
      a = __builtin_amdgcn_mfma_f32_16x16x32_bf16(bh1, AL1[ta], a, 0,0,0);
      int m = m0 + ta*16 + row;
      if (m < E){
        float4 v;
        v.x = fmaxf(a[0]+bias.x, 0.f); v.y = fmaxf(a[1]+bias.y, 0.f);
        v.z = fmaxf(a[2]+bias.z, 0.f); v.w = fmaxf(a[3]+bias.w, 0.f);
        *(float4*)(hidden + (size_t)m*128 + n0 + tb*16 + quad*4) = v;
      }
    }
  }
}

// ---------------- Q GEMM via split-bf16 MFMA, swapped operands, direct stores -----
__global__ __launch_bounds__(256,3) void k_qgemm_mfma(
    const u16* __restrict__ Ah, const u16* __restrict__ Al,
    const u16* __restrict__ BhT, const u16* __restrict__ BlT,
    float* __restrict__ C, int M)
{
  const int lane = threadIdx.x & 63;
  const int wave = threadIdx.x >> 6;
  const int row  = lane & 15;
  const int quad = lane >> 4;
  const int m0 = blockIdx.y * 64;
  const int n0 = blockIdx.x * 256 + wave * 64;

  bf16x8 AH0[4], AH1[4], AL0[4], AL1[4];
  #pragma unroll
  for (int p=0;p<4;p++){
    int ar = min(m0 + p*16 + row, M-1);
    const u16* aH = Ah + (size_t)ar*64 + quad*8;
    const u16* aL = Al + (size_t)ar*64 + quad*8;
    AH0[p] = *(const bf16x8*)(aH);
    AH1[p] = *(const bf16x8*)(aH + 32);
    AL0[p] = *(const bf16x8*)(aL);
    AL1[p] = *(const bf16x8*)(aL + 32);
  }

  #pragma unroll
  for (int tb=0;tb<4;tb++){
    const u16* bH = BhT + (size_t)(n0 + tb*16 + row)*64 + quad*8;
    const u16* bL = BlT + (size_t)(n0 + tb*16 + row)*64 + quad*8;
    bf16x8 bh0 = *(const bf16x8*)(bH);
    bf16x8 bh1 = *(const bf16x8*)(bH + 32);
    bf16x8 bl0 = *(const bf16x8*)(bL);
    bf16x8 bl1 = *(const bf16x8*)(bL + 32);
    #pragma unroll
    for (int ta=0;ta<4;ta++){
      f32x4 a = {0.f,0.f,0.f,0.f};
      a = __builtin_amdgcn_mfma_f32_16x16x32_bf16(bh0, AH0[ta], a, 0,0,0);
      a = __builtin_amdgcn_mfma_f32_16x16x32_bf16(bh1, AH1[ta], a, 0,0,0);
      a = __builtin_amdgcn_mfma_f32_16x16x32_bf16(bl0, AH0[ta], a, 0,0,0);
      a = __builtin_amdgcn_mfma_f32_16x16x32_bf16(bl1, AH1[ta], a, 0,0,0);
      a = __builtin_amdgcn_mfma_f32_16x16x32_bf16(bh0, AL0[ta], a, 0,0,0);
      a = __builtin_amdgcn_mfma_f32_16x16x32_bf16(bh1, AL1[ta], a, 0,0,0);
      int m = m0 + ta*16 + row;
      if (m < M){
        float4 v; v.x=a[0]; v.y=a[1]; v.z=a[2]; v.w=a[3];
        *(float4*)(C + (size_t)m*4096 + n0 + tb*16 + quad*4) = v;
      }
    }
  }
}

// ---------------- edge gather v2: 2 edges/wave, no barriers ----------------
template<int PASS>
__global__ __launch_bounds__(256) void k_edge_gather(const float* __restrict__ Q,
    const float* __restrict__ hidden, int h0,
    const float* __restrict__ bterm, const int* __restrict__ srcS,
    const int* __restrict__ dstS,
    float* __restrict__ msg, float* __restrict__ agg, int E)
{
  __shared__ float hs[4][2][64];
  __shared__ float red[4][2][64];
  const int wv = threadIdx.x>>6, lane = threadIdx.x&63;
  const int ew0 = (blockIdx.x*4 + wv)*2;
  const bool v0 = (ew0 < E), v1 = (ew0+1 < E);
  const int e0 = v0 ? ew0 : 0;
  const int e1 = v1 ? ew0+1 : 0;
  const int s0 = srcS[e0], s1 = srcS[e1];
  hs[wv][0][lane] = hidden[(size_t)e0*128 + h0 + lane];
  hs[wv][1][lane] = hidden[(size_t)e1*128 + h0 + lane];
  // per-wave LDS only: in-wave lgkmcnt ordering suffices, no __syncthreads
  const int sg = lane>>4, oq = lane&15;
  const float* q0 = Q + (size_t)s0*4096 + sg*64 + oq*4;
  const float* q1 = Q + (size_t)s1*4096 + sg*64 + oq*4;
  float a00=0.f,a01=0.f,a02=0.f,a03=0.f;
  float a10=0.f,a11=0.f,a12=0.f,a13=0.f;
  #pragma unroll
  for (int j=0;j<16;j++){
    float4 qa = *(const float4*)(q0 + j*256);
    float4 qb = *(const float4*)(q1 + j*256);
    float h0v = hs[wv][0][j*4 + sg];
    float h1v = hs[wv][1][j*4 + sg];
    a00 = fmaf(h0v, qa.x, a00); a01 = fmaf(h0v, qa.y, a01);
    a02 = fmaf(h0v, qa.z, a02); a03 = fmaf(h0v, qa.w, a03);
    a10 = fmaf(h1v, qb.x, a10); a11 = fmaf(h1v, qb.y, a11);
    a12 = fmaf(h1v, qb.z, a12); a13 = fmaf(h1v, qb.w, a13);
  }
  a00 += __shfl_xor(a00,16); a00 += __shfl_xor(a00,32);
  a01 += __shfl_xor(a01,16); a01 += __shfl_xor(a01,32);
  a02 += __shfl_xor(a02,16); a02 += __shfl_xor(a02,32);
  a03 += __shfl_xor(a03,16); a03 += __shfl_xor(a03,32);
  a10 += __shfl_xor(a10,16); a10 += __shfl_xor(a10,32);
  a11 += __shfl_xor(a11,16); a11 += __shfl_xor(a11,32);
  a12 += __shfl_xor(a12,16); a12 += __shfl_xor(a12,32);
  a13 += __shfl_xor(a13,16); a13 += __shfl_xor(a13,32);
  if (lane < 16){
    float4 r0; r0.x=a00; r0.y=a01; r0.z=a02; r0.w=a03;
    float4 r1; r1.x=a10; r1.y=a11; r1.z=a12; r1.w=a13;
    *(float4*)&red[wv][0][lane*4] = r0;
    *(float4*)&red[wv][1][lane*4] = r1;
  }
  // in-wave lgkmcnt ordering; no barrier
  if (v0){
    float rv = red[wv][0][lane];
    if (PASS == 0) msg[(size_t)ew0*64 + lane] = bterm[(size_t)s0*64 + lane] + rv;
    else atomicAdd(&agg[(size_t)dstS[ew0]*64 + lane], msg[(size_t)ew0*64 + lane] + rv);
  }
  if (v1){
    float rv = red[wv][1][lane];
    if (PASS == 0) msg[(size_t)(ew0+1)*64 + lane] = bterm[(size_t)s1*64 + lane] + rv;
    else atomicAdd(&agg[(size_t)dstS[ew0+1]*64 + lane], msg[(size_t)(ew0+1)*64 + lane] + rv);
  }
}

// ---------------- agg-normalize + root + GRU + bf16 shadow + fused bterm ---------
__global__ __launch_bounds__(256) void k_node_update(const float* __restrict__ outOld,
    const float* __restrict__ agg, const float* __restrict__ deg,
    const float* __restrict__ rootT, const float* __restrict__ conv_b,
    const float* __restrict__ wihT, const float* __restrict__ whhT,
    const float* __restrict__ b_ih, const float* __restrict__ b_hh,
    const float* __restrict__ nn2_b,
    float* __restrict__ outNew, u16* __restrict__ outH, u16* __restrict__ outL,
    float* __restrict__ bterm, int N)
{
  __shared__ float hs[4][64];
  __shared__ float ms[4][64];
  int ln = threadIdx.x>>6, o = threadIdx.x&63;
  int n = blockIdx.x*4+ln;
  bool ok = (n<N);
  float h = ok ? outOld[(size_t)n*64+o] : 0.f;
  hs[ln][o] = h;
  __syncthreads();
  float root = 0.f;
  #pragma unroll 8
  for (int i=0;i<64;i++) root = fmaf(hs[ln][i], rootT[i*64+o], root);
  float d = ok ? fmaxf(deg[n], 1.f) : 1.f;
  float a = ok ? agg[(size_t)n*64+o]/d : 0.f;
  float m = fmaxf(a + root + conv_b[o], 0.f);
  ms[ln][o] = m;
  __syncthreads();
  float gir=b_ih[o], giz=b_ih[64+o], gin=b_ih[128+o];
  float ghr=b_hh[o], ghz=b_hh[64+o], ghn=b_hh[128+o];
  #pragma unroll 4
  for (int i=0;i<64;i++){
    float mi = ms[ln][i], hi = hs[ln][i];
    gir = fmaf(mi, wihT[i*192+o],      gir);
    giz = fmaf(mi, wihT[i*192+64+o],   giz);
    gin = fmaf(mi, wihT[i*192+128+o],  gin);
    ghr = fmaf(hi, whhT[i*192+o],      ghr);
    ghz = fmaf(hi, whhT[i*192+64+o],   ghz);
    ghn = fmaf(hi, whhT[i*192+128+o],  ghn);
  }
  float r = sigmoidf_(gir+ghr);
  float z = sigmoidf_(giz+ghz);
  float nn = tanhf(gin + r*ghn);
  if (ok){
    float v = (1.f-z)*nn + z*h;
    outNew[(size_t)n*64+o] = v;
    u16 hi16, lo16; split_bf(v, hi16, lo16);
    outH[(size_t)n*64+o] = hi16;
    outL[(size_t)n*64+o] = lo16;
    float bt = 0.f;
    #pragma unroll 8
    for (int i=0;i<64;i++) bt = fmaf(__shfl(v, i, 64), nn2_b[i*64+o], bt);
    bterm[(size_t)n*64+o] = bt;
  }
}

// ---------------- Set2Set (3 steps) + final MLP: LDS-staged, one block/graph -------
__global__ __launch_bounds__(256) void k_set2set(const float* __restrict__ out,
    const int* __restrict__ batch, int N,
    const float* __restrict__ lwihT, const float* __restrict__ lwhhT,
    const float* __restrict__ b_ih, const float* __restrict__ b_hh,
    const float* __restrict__ lin1T, const float* __restrict__ lin1_b,
    const float* __restrict__ lin2_w, const float* __restrict__ lin2_b,
    float* __restrict__ y)
{
  __shared__ float X[S2CAP][65];
  __shared__ float earr[S2CAP];
  __shared__ float qstar[128], hl[64], cl[64], g[256];
  __shared__ float rpart[4][64], spart[4], redm[4], zs[64];
  __shared__ int sb[2];
  const int tid = threadIdx.x;
  const int b = blockIdx.x;
  const int wid = tid>>6, lane = tid&63;
  if (tid < 128) qstar[tid] = 0.f;
  if (tid < 64){ hl[tid]=0.f; cl[tid]=0.f; }
  if (tid == 0){
    int lo=0, hi=N;
    while (lo<hi){ int mid=(lo+hi)>>1; if (batch[mid] < b) lo=mid+1; else hi=mid; }
    sb[0]=lo;
    int lo2=lo, hi2=N;
    while (lo2<hi2){ int mid=(lo2+hi2)>>1; if (batch[mid] < b+1) lo2=mid+1; else hi2=mid; }
    sb[1]=lo2;
  }
  __syncthreads();
  const int nlo = sb[0], nhi = sb[1], nn = nhi - nlo;
  const bool single = (nn <= S2CAP);
  if (single){
    for (int idx = tid; idx < nn*64; idx += 256){
      X[idx>>6][idx&63] = out[(size_t)(nlo + (idx>>6))*64 + (idx&63)];
    }
  }
  __syncthreads();

  for (int step=0; step<3; step++){
    float gs = b_ih[tid] + b_hh[tid];
    for (int j=0;j<128;j++) gs = fmaf(qstar[j], lwihT[j*256+tid], gs);
    for (int j=0;j<64;j++)  gs = fmaf(hl[j],    lwhhT[j*256+tid], gs);
    g[tid] = gs;
    __syncthreads();
    if (tid < 64){
      float ig = sigmoidf_(g[tid]);
      float fg = sigmoidf_(g[64+tid]);
      float gg = tanhf(g[128+tid]);
      float og = sigmoidf_(g[192+tid]);
      float c = fg*cl[tid] + ig*gg;
      cl[tid] = c;
      hl[tid] = og*tanhf(c);
    }
    __syncthreads();

    if (single){
      float lm = -INFINITY;
      for (int n = tid; n < nn; n += 256){
        float acc = 0.f;
        #pragma unroll 8
        for (int d=0; d<64; d++) acc = fmaf(X[n][d], hl[d], acc);
        earr[n] = acc;
        lm = fmaxf(lm, acc);
      }
      lm = fmaxf(lm, __shfl_xor(lm,1));  lm = fmaxf(lm, __shfl_xor(lm,2));
      lm = fmaxf(lm, __shfl_xor(lm,4));  lm = fmaxf(lm, __shfl_xor(lm,8));
      lm = fmaxf(lm, __shfl_xor(lm,16)); lm = fmaxf(lm, __shfl_xor(lm,32));
      if (lane==0) redm[wid] = lm;
      __syncthreads();
      if (tid==0) redm[0] = fmaxf(fmaxf(redm[0],redm[1]), fmaxf(redm[2],redm[3]));
      __syncthreads();
      const float gmax = redm[0];
      float ls = 0.f;
      for (int n = tid; n < nn; n += 256){
        float a = expf(earr[n] - gmax);
        earr[n] = a;
        ls += a;
      }
      ls += __shfl_xor(ls,1);  ls += __shfl_xor(ls,2);  ls += __shfl_xor(ls,4);
      ls += __shfl_xor(ls,8);  ls += __shfl_xor(ls,16); ls += __shfl_xor(ls,32);
      if (lane==0) spart[wid] = ls;
      __syncthreads();
      float racc = 0.f;
      for (int n = wid; n < nn; n += 4) racc = fmaf(earr[n], X[n][lane], racc);
      rpart[wid][lane] = racc;
      __syncthreads();
      if (tid < 64){
        float r = rpart[0][tid]+rpart[1][tid]+rpart[2][tid]+rpart[3][tid];
        float s = spart[0]+spart[1]+spart[2]+spart[3];
        qstar[tid] = hl[tid];
        qstar[64+tid] = (nn>0) ? r/s : 0.f;
      }
      __syncthreads();
    } else {
      float qv = hl[lane];
      float lm = -INFINITY;
      for (int n = nlo + wid; n < nhi; n += 4){
        float p = out[(size_t)n*64 + lane]*qv;
        p += __shfl_xor(p,1); p += __shfl_xor(p,2); p += __shfl_xor(p,4);
        p += __shfl_xor(p,8); p += __shfl_xor(p,16); p += __shfl_xor(p,32);
        lm = fmaxf(lm, p);
      }
      if (lane==0) redm[wid] = lm;
      __syncthreads();
      if (tid==0) redm[0] = fmaxf(fmaxf(redm[0],redm[1]), fmaxf(redm[2],redm[3]));
      __syncthreads();
      float gmax = redm[0];
      float sw = 0.f, racc = 0.f;
      for (int n = nlo + wid; n < nhi; n += 4){
        float ol = out[(size_t)n*64 + lane];
        float p = ol*qv;
        p += __shfl_xor(p,1); p += __shfl_xor(p,2); p += __shfl_xor(p,4);
        p += __shfl_xor(p,8); p += __shfl_xor(p,16); p += __shfl_xor(p,32);
        float a = expf(p - gmax);
        sw += a;
        racc = fmaf(a, ol, racc);
      }
      rpart[wid][lane] = racc;
      if (lane==0) spart[wid] = sw;
      __syncthreads();
      if (tid < 64){
        float r = rpart[0][tid]+rpart[1][tid]+rpart[2][tid]+rpart[3][tid];
        float s = spart[0]+spart[1]+spart[2]+spart[3];
        qstar[tid] = hl[tid];
        qstar[64+tid] = (nn>0) ? r/s : 0.f;
      }
      __syncthreads();
    }
  }
  if (tid < 64){
    float acc = lin1_b[tid];
    for (int j=0;j<128;j++) acc = fmaf(qstar[j], lin1T[j*64+tid], acc);
    zs[tid] = fmaxf(acc, 0.f);
  }
  __syncthreads();
  if (tid < 64){
    float v = zs[lane]*lin2_w[lane];
    v += __shfl_xor(v,1); v += __shfl_xor(v,2); v += __shfl_xor(v,4);
    v += __shfl_xor(v,8); v += __shfl_xor(v,16); v += __shfl_xor(v,32);
    if (lane==0) y[b] = v + lin2_b[0];
  }
}

extern "C" void kernel_launch(void* const* d_in, const int* in_sizes, int n_in,
                              void* d_out, int out_size, void* d_ws, size_t ws_size,
                              hipStream_t stream)
{
  const float* x      = (const float*)d_in[0];
  const float* eattr  = (const float*)d_in[1];
  const float* lin0_w = (const float*)d_in[2];
  const float* lin0_b = (const float*)d_in[3];
  const float* nn1_w  = (const float*)d_in[4];
  const float* nn1_b  = (const float*)d_in[5];
  const float* nn2_w  = (const float*)d_in[6];
  const float* nn2_b  = (const float*)d_in[7];
  const float* root_w = (const float*)d_in[8];
  const float* conv_b = (const float*)d_in[9];
  const float* gwih   = (const float*)d_in[10];
  const float* gwhh   = (const float*)d_in[11];
  const float* gbih   = (const float*)d_in[12];
  const float* gbhh   = (const float*)d_in[13];
  const float* lwih   = (const float*)d_in[14];
  const float* lwhh   = (const float*)d_in[15];
  const float* lbih   = (const float*)d_in[16];
  const float* lbhh   = (const float*)d_in[17];
  const float* lin1_w = (const float*)d_in[18];
  const float* lin1_b = (const float*)d_in[19];
  const float* lin2_w = (const float*)d_in[20];
  const float* lin2_b = (const float*)d_in[21];
  const int*   eidx   = (const int*)d_in[22];
  const int*   batch  = (const int*)d_in[23];

  const int N = in_sizes[0]/FN;
  const int E = in_sizes[1]/FE;
  const int* srcI = eidx;
  const int* dstI = eidx + E;

  char* w = (char*)d_ws;
  size_t off = 0;
  auto alloc = [&](size_t bytes)->char* {
    char* p = w + off;
    off = (off + bytes + 255) & ~(size_t)255;
    return p;
  };
  float* degw  = (float*)alloc((size_t)N*4);
  int*   scnt  = (int*)alloc((size_t)N*4);
  int*   starts= (int*)alloc((size_t)(N+1)*4);
  int*   cursor= (int*)alloc((size_t)N*4);
  int*   bsum  = (int*)alloc((size_t)256*4);
  int*   sortedE=(int*)alloc((size_t)E*4);
  int*   srcS  = (int*)alloc((size_t)E*4);
  int*   dstS  = (int*)alloc((size_t)E*4);
  float* outA  = (float*)alloc((size_t)N*64*4);
  float* outB  = (float*)alloc((size_t)N*64*4);
  u16*   outAH = (u16*)alloc((size_t)N*64*2);
  u16*   outAL = (u16*)alloc((size_t)N*64*2);
  u16*   outBH = (u16*)alloc((size_t)N*64*2);
  u16*   outBL = (u16*)alloc((size_t)N*64*2);
  float* agg   = (float*)alloc((size_t)N*64*4);
  float* bterm = (float*)alloc((size_t)N*64*4);
  float* hidden= (float*)alloc((size_t)E*128*4);
  float* msg   = (float*)alloc((size_t)E*64*4);
  u16*   B2hT  = (u16*)alloc((size_t)524288*2);
  u16*   B2lT  = (u16*)alloc((size_t)524288*2);
  u16*   BT1h  = (u16*)alloc((size_t)8192*2);
  u16*   BT1l  = (u16*)alloc((size_t)8192*2);
  float* lin0T = (float*)alloc((size_t)92*64*4);
  float* nn1T  = (float*)alloc((size_t)41*128*4);
  float* rootT = (float*)alloc((size_t)64*64*4);
  float* wihT  = (float*)alloc((size_t)64*192*4);
  float* whhT  = (float*)alloc((size_t)64*192*4);
  float* lwihT = (float*)alloc((size_t)128*256*4);
  float* lwhhT = (float*)alloc((size_t)64*256*4);
  float* lin1T = (float*)alloc((size_t)128*64*4);
  float* Q     = (float*)alloc((size_t)N*4096*4);   // one 64-h chunk: [n][h*64+o]
  // eaH/eaL overlay Q's buffer: consumed by k_edge_mlp_mfma before first qgemm write
  u16* eaH = (u16*)Q;
  u16* eaL = eaH + (size_t)E*64;

  const int NB = (N+255)/256;

  hipMemsetAsync(degw, 0, (size_t)N*4, stream);
  hipMemsetAsync(scnt, 0, (size_t)N*4, stream);
  k_pack<<<(97152+255)/256, 256, 0, stream>>>(lin0_w, nn1_w, root_w, gwih, gwhh,
      lwih, lwhh, lin1_w, lin0T, nn1T, rootT, wihT, whhT, lwihT, lwhhT, lin1T);
  k_pack_b2<<<524288/256, 256, 0, stream>>>(nn2_w, B2hT, B2lT);
  k_pack_b1<<<8192/256, 256, 0, stream>>>(nn1_w, BT1h, BT1l);
  k_node_mlp<<<(N+3)/4, 256, 0, stream>>>(x, lin0T, lin0_b, nn2_b, outA, outAH, outAL, bterm, N);
  k_count<<<(E+255)/256, 256, 0, stream>>>(dstI, srcI, degw, scnt, E);
  k_scan1<<<NB, 256, 0, stream>>>(scnt, starts, bsum, N);
  k_scan2<<<1, 256, 0, stream>>>(bsum, NB);
  k_scan3<<<NB, 256, 0, stream>>>(starts, cursor, bsum, N, E);
  k_sort<<<(E+255)/256, 256, 0, stream>>>(srcI, dstI, cursor, sortedE, srcS, dstS, E);
  k_split_ea<<<((size_t)E*64+255)/256, 256, 0, stream>>>(eattr, sortedE, eaH, eaL, E);
  k_edge_mlp_mfma<<<(E+127)/128, 256, 0, stream>>>(eaH, eaL, BT1h, BT1l, nn1_b, hidden, E);

  float* cur = outA; float* nxt = outB;
  u16* curH = outAH; u16* curL = outAL;
  u16* nxtH = outBH; u16* nxtL = outBL;
  const dim3 qgrid(16, (N+63)/64);
  const int gatherGx = (E+7)/8;
  for (int conv=0; conv<2; conv++){
    hipMemsetAsync(agg, 0, (size_t)N*64*4, stream);
    // chunk 0 (h in [0,64))
    k_qgemm_mfma<<<qgrid, 256, 0, stream>>>(curH, curL, B2hT, B2lT, Q, N);
    k_edge_gather<0><<<gatherGx, 256, 0, stream>>>(Q, hidden, 0, bterm, srcS, dstS, msg, agg, E);
    // chunk 1 (h in [64,128))
    k_qgemm_mfma<<<qgrid, 256, 0, stream>>>(curH, curL, B2hT + 262144, B2lT + 262144, Q, N);
    k_edge_gather<1><<<gatherGx, 256, 0, stream>>>(Q, hidden, 64, bterm, srcS, dstS, msg, agg, E);
    k_node_update<<<(N+3)/4, 256, 0, stream>>>(cur, agg, degw, rootT, conv_b,
        wihT, whhT, gbih, gbhh, nn2_b, nxt, nxtH, nxtL, bterm, N);
    float* t = cur; cur = nxt; nxt = t;
    u16* th = curH; curH = nxtH; nxtH = th;
    u16* tl = curL; curL = nxtL; nxtL = tl;
  }

  k_set2set<<<128, 256, 0, stream>>>(cur, batch, N, lwihT, lwhhT, lbih, lbhh,
      lin1T, lin1_b, lin2_w, lin2_b, (float*)d_out);
}

// Round 15
// 633.322 us; speedup vs baseline: 1.1364x; 1.0707x over previous
//
#include <hip/hip_runtime.h>
#include <hip/hip_bf16.h>
#include <math.h>

#define DD 64
#define HIDC 128
#define FN 92
#define FE 41
#define S2CAP 192

typedef unsigned short u16;
typedef short bf16x8 __attribute__((ext_vector_type(8)));
typedef float f32x4 __attribute__((ext_vector_type(4)));

__device__ __forceinline__ float sigmoidf_(float x){ return 1.f/(1.f+expf(-x)); }

__device__ __forceinline__ u16 f2bf(float v){
  union { float f; unsigned u; } x; x.f = v;
  unsigned r = x.u + 0x7fff + ((x.u >> 16) & 1);
  return (u16)(r >> 16);
}
__device__ __forceinline__ float bf2f(u16 v){
  union { float f; unsigned u; } x; x.u = ((unsigned)v) << 16;
  return x.f;
}
__device__ __forceinline__ void split_bf(float v, u16& h, u16& l){
  h = f2bf(v); l = f2bf(v - bf2f(h));
}

// ---------------- pack/transpose small weights ----------------
__global__ void k_pack(const float* __restrict__ lin0_w, const float* __restrict__ nn1_w,
                       const float* __restrict__ root_w, const float* __restrict__ gwih,
                       const float* __restrict__ gwhh, const float* __restrict__ lwih,
                       const float* __restrict__ lwhh, const float* __restrict__ lin1_w,
                       float* __restrict__ lin0T, float* __restrict__ nn1T,
                       float* __restrict__ rootT, float* __restrict__ wihT,
                       float* __restrict__ whhT, float* __restrict__ lwihT,
                       float* __restrict__ lwhhT, float* __restrict__ lin1T)
{
  int idx = blockIdx.x*blockDim.x + threadIdx.x;
  if (idx < 92*64){ int k=idx/64, o=idx%64; lin0T[k*64+o] = lin0_w[o*92+k]; return; } idx -= 92*64;
  if (idx < 41*128){ int k=idx/128, h=idx%128; nn1T[k*128+h] = nn1_w[h*41+k]; return; } idx -= 41*128;
  if (idx < 64*64){ int i=idx/64, o=idx%64; rootT[i*64+o] = root_w[o*64+i]; return; } idx -= 64*64;
  if (idx < 64*192){ int i=idx/192, g=idx%192; wihT[i*192+g] = gwih[g*64+i]; return; } idx -= 64*192;
  if (idx < 64*192){ int i=idx/192, g=idx%192; whhT[i*192+g] = gwhh[g*64+i]; return; } idx -= 64*192;
  if (idx < 128*256){ int j=idx/256, t=idx%256; lwihT[j*256+t] = lwih[t*128+j]; return; } idx -= 128*256;
  if (idx < 64*256){ int j=idx/256, t=idx%256; lwhhT[j*256+t] = lwhh[t*64+j]; return; } idx -= 64*256;
  if (idx < 128*64){ int j=idx/64, t=idx%64; lin1T[j*64+t] = lin1_w[t*128+j]; return; }
}

// Split nn2_w into bf16 hi/lo, transposed for MFMA B-fragments:
// BT[c*262144 + (h*64+o)*64 + i] = nn2_w[(i*64+o)*128 + c*64 + h]   (c = 64-h chunk)
__global__ void k_pack_b2(const float* __restrict__ nn2_w,
                          u16* __restrict__ BhT, u16* __restrict__ BlT){
  int idx = blockIdx.x*256 + threadIdx.x;
  if (idx >= 524288) return;
  int i  = idx & 63;
  int ho = (idx >> 6) & 4095;
  int c  = idx >> 18;
  int h = ho >> 6, o = ho & 63;
  float v = nn2_w[(size_t)(i*64+o)*128 + c*64 + h];
  u16 hi, lo; split_bf(v, hi, lo);
  BhT[idx] = hi; BlT[idx] = lo;
}

// nn1_w [128,41] -> B-fragment layout [h][k] padded K=64, bf16 hi/lo
__global__ void k_pack_b1(const float* __restrict__ nn1_w,
                          u16* __restrict__ BT1h, u16* __restrict__ BT1l){
  int idx = blockIdx.x*256 + threadIdx.x;
  if (idx >= 8192) return;
  int h = idx >> 6, k = idx & 63;
  float v = (k < FE) ? nn1_w[(size_t)h*FE + k] : 0.f;
  u16 hi, lo; split_bf(v, hi, lo);
  BT1h[idx] = hi; BT1l[idx] = lo;
}

// gather ea rows into sorted order, split bf16 hi/lo, pad K 41->64
__global__ void k_split_ea(const float* __restrict__ ea, const int* __restrict__ sortedE,
                           u16* __restrict__ eaH, u16* __restrict__ eaL, int E){
  int idx = blockIdx.x*256 + threadIdx.x;
  if (idx >= E*64) return;
  int ew = idx >> 6, k = idx & 63;
  int e = sortedE[ew];
  float v = (k < FE) ? ea[(size_t)e*FE + k] : 0.f;
  u16 hi, lo; split_bf(v, hi, lo);
  eaH[idx] = hi; eaL[idx] = lo;
}

// ---------------- node MLP + bf16 shadow + fused bterm ----------------
__global__ __launch_bounds__(256) void k_node_mlp(const float* __restrict__ x,
    const float* __restrict__ lin0T, const float* __restrict__ lin0_b,
    const float* __restrict__ nn2_b,
    float* __restrict__ out, u16* __restrict__ outH, u16* __restrict__ outL,
    float* __restrict__ bterm, int N)
{
  __shared__ float xs[4][FN];
  int base = blockIdx.x*4;
  for (int i=threadIdx.x; i<4*FN; i+=256){
    int n = base + i/FN;
    xs[i/FN][i%FN] = (n<N) ? x[(size_t)n*FN + i%FN] : 0.f;
  }
  __syncthreads();
  int ln = threadIdx.x>>6, o = threadIdx.x&63;
  int n = base+ln;
  if (n>=N) return;
  float acc = lin0_b[o];
  #pragma unroll 4
  for (int k=0;k<FN;k++) acc = fmaf(xs[ln][k], lin0T[k*64+o], acc);
  float v = fmaxf(acc, 0.f);
  out[(size_t)n*64+o] = v;
  u16 hi, lo; split_bf(v, hi, lo);
  outH[(size_t)n*64+o] = hi;
  outL[(size_t)n*64+o] = lo;
  float bt = 0.f;
  #pragma unroll 8
  for (int i=0;i<64;i++) bt = fmaf(__shfl(v, i, 64), nn2_b[i*64+o], bt);
  bterm[(size_t)n*64+o] = bt;
}

// ---------------- degree + src histogram ----------------
__global__ void k_count(const int* __restrict__ dst, const int* __restrict__ src,
                        float* __restrict__ deg, int* __restrict__ scnt, int E){
  int e = blockIdx.x*blockDim.x + threadIdx.x;
  if (e < E){
    atomicAdd(&deg[dst[e]], 1.f);
    atomicAdd(&scnt[src[e]], 1);
  }
}

// ---------------- 3-kernel exclusive scan over scnt[N] ----------------
__global__ void k_scan1(const int* __restrict__ cnt, int* __restrict__ excl,
                        int* __restrict__ bsum, int N){
  __shared__ int buf[256];
  int i = blockIdx.x*256 + threadIdx.x;
  int v = (i<N) ? cnt[i] : 0;
  buf[threadIdx.x] = v;
  __syncthreads();
  #pragma unroll
  for (int off=1; off<256; off<<=1){
    int t = (threadIdx.x>=off) ? buf[threadIdx.x-off] : 0;
    __syncthreads();
    buf[threadIdx.x] += t;
    __syncthreads();
  }
  if (i<N) excl[i] = buf[threadIdx.x] - v;
  if (threadIdx.x==255) bsum[blockIdx.x] = buf[255];
}
__global__ void k_scan2(int* __restrict__ bsum, int nb){
  __shared__ int buf[256];
  int v = (threadIdx.x<nb) ? bsum[threadIdx.x] : 0;
  buf[threadIdx.x] = v;
  __syncthreads();
  #pragma unroll
  for (int off=1; off<256; off<<=1){
    int t = (threadIdx.x>=off) ? buf[threadIdx.x-off] : 0;
    __syncthreads();
    buf[threadIdx.x] += t;
    __syncthreads();
  }
  if (threadIdx.x<nb) bsum[threadIdx.x] = buf[threadIdx.x] - v;
}
__global__ void k_scan3(int* __restrict__ starts, int* __restrict__ cursor,
                        const int* __restrict__ bsum, int N, int E){
  int i = blockIdx.x*256 + threadIdx.x;
  if (i<N){
    int s = starts[i] + bsum[blockIdx.x];
    starts[i] = s;
    cursor[i] = s;
  }
  if (i==0) starts[N] = E;
}

// ---------------- scatter: sortedE grouped by src, + sorted src/dst arrays -------
__global__ void k_sort(const int* __restrict__ src, const int* __restrict__ dst,
                       int* __restrict__ cursor, int* __restrict__ sortedE,
                       int* __restrict__ srcS, int* __restrict__ dstS, int E){
  int e = blockIdx.x*256 + threadIdx.x;
  if (e < E){
    int s = src[e];
    int p = atomicAdd(&cursor[s], 1);
    sortedE[p] = e;
    srcS[p] = s;
    dstS[p] = dst[e];
  }
}

// ---------------- edge MLP via split-bf16 MFMA, swapped operands, direct stores ----
__global__ __launch_bounds__(256,3) void k_edge_mlp_mfma(
    const u16* __restrict__ eaH, const u16* __restrict__ eaL,
    const u16* __restrict__ BT1h, const u16* __restrict__ BT1l,
    const float* __restrict__ nn1_b, float* __restrict__ hidden, int E)
{
  const int lane = threadIdx.x & 63;
  const int wave = threadIdx.x >> 6;
  const int row  = lane & 15;
  const int quad = lane >> 4;
  const int m0 = blockIdx.x*128 + (wave>>1)*64;
  const int n0 = (wave&1)*64;

  bf16x8 AH0[4], AH1[4], AL0[4], AL1[4];
  #pragma unroll
  for (int p=0;p<4;p++){
    int ar = min(m0 + p*16 + row, E-1);
    const u16* aH = eaH + (size_t)ar*64 + quad*8;
    const u16* aL = eaL + (size_t)ar*64 + quad*8;
    AH0[p] = *(const bf16x8*)(aH);
    AH1[p] = *(const bf16x8*)(aH + 32);
    AL0[p] = *(const bf16x8*)(aL);
    AL1[p] = *(const bf16x8*)(aL + 32);
  }
  #pragma unroll
  for (int tb=0;tb<4;tb++){
    const u16* bH = BT1h + (size_t)(n0 + tb*16 + row)*64 + quad*8;
    const u16* bL = BT1l + (size_t)(n0 + tb*16 + row)*64 + quad*8;
    bf16x8 bh0 = *(const bf16x8*)(bH);
    bf16x8 bh1 = *(const bf16x8*)(bH + 32);
    bf16x8 bl0 = *(const bf16x8*)(bL);
    bf16x8 bl1 = *(const bf16x8*)(bL + 32);
    float4 bias;
    {
      int nb = n0 + tb*16 + quad*4;
      bias.x = nn1_b[nb+0]; bias.y = nn1_b[nb+1];
      bias.z = nn1_b[nb+2]; bias.w = nn1_b[nb+3];
    }
    #pragma unroll
    for (int ta=0;ta<4;ta++){
      f32x4 a = {0.f,0.f,0.f,0.f};
      a = __builtin_amdgcn_mfma_f32_16x16x32_bf16(bh0, AH0[ta], a, 0,0,0);
      a = __builtin_amdgcn_mfma_f32_16x16x32_bf16(bh1, AH1[ta], a, 0,0,0);
      a = __builtin_amdgcn_mfma_f32_16x16x32_bf16(bl0, AH0[ta], a, 0,0,0);
      a = __builtin_amdgcn_mfma_f32_16x16x32_bf16(bl1, AH1[ta], a, 0,0,0);
      a = __builtin_amdgcn_mfma_f32_16x16x32_bf16(bh0, AL0[ta], a, 0,0,0);
      a = __builtin_amdgcn_mfma_f32_16x16x32_bf16(bh1, AL1[ta], a, 0,0,0);
      int m = m0 + ta*16 + row;
      if (m < E){
        float4 v;
        v.x = fmaxf(a[0]+bias.x, 0.f); v.y = fmaxf(a[1]+bias.y, 0.f);
        v.z = fmaxf(a[2]+bias.z, 0.f); v.w = fmaxf(a[3]+bias.w, 0.f);
        *(float4*)(hidden + (size_t)m*128 + n0 + tb*16 + quad*4) = v;
      }
    }
  }
}

// ---------------- Q GEMM via split-bf16 MFMA, swapped operands, bf16 output -------
__global__ __launch_bounds__(256,3) void k_qgemm_mfma(
    const u16* __restrict__ Ah, const u16* __restrict__ Al,
    const u16* __restrict__ BhT, const u16* __restrict__ BlT,
    u16* __restrict__ C, int M)
{
  const int lane = threadIdx.x & 63;
  const int wave = threadIdx.x >> 6;
  const int row  = lane & 15;
  const int quad = lane >> 4;
  const int m0 = blockIdx.y * 64;
  const int n0 = blockIdx.x * 256 + wave * 64;

  bf16x8 AH0[4], AH1[4], AL0[4], AL1[4];
  #pragma unroll
  for (int p=0;p<4;p++){
    int ar = min(m0 + p*16 + row, M-1);
    const u16* aH = Ah + (size_t)ar*64 + quad*8;
    const u16* aL = Al + (size_t)ar*64 + quad*8;
    AH0[p] = *(const bf16x8*)(aH);
    AH1[p] = *(const bf16x8*)(aH + 32);
    AL0[p] = *(const bf16x8*)(aL);
    AL1[p] = *(const bf16x8*)(aL + 32);
  }

  #pragma unroll
  for (int tb=0;tb<4;tb++){
    const u16* bH = BhT + (size_t)(n0 + tb*16 + row)*64 + quad*8;
    const u16* bL = BlT + (size_t)(n0 + tb*16 + row)*64 + quad*8;
    bf16x8 bh0 = *(const bf16x8*)(bH);
    bf16x8 bh1 = *(const bf16x8*)(bH + 32);
    bf16x8 bl0 = *(const bf16x8*)(bL);
    bf16x8 bl1 = *(const bf16x8*)(bL + 32);
    #pragma unroll
    for (int ta=0;ta<4;ta++){
      f32x4 a = {0.f,0.f,0.f,0.f};
      a = __builtin_amdgcn_mfma_f32_16x16x32_bf16(bh0, AH0[ta], a, 0,0,0);
      a = __builtin_amdgcn_mfma_f32_16x16x32_bf16(bh1, AH1[ta], a, 0,0,0);
      a = __builtin_amdgcn_mfma_f32_16x16x32_bf16(bl0, AH0[ta], a, 0,0,0);
      a = __builtin_amdgcn_mfma_f32_16x16x32_bf16(bl1, AH1[ta], a, 0,0,0);
      a = __builtin_amdgcn_mfma_f32_16x16x32_bf16(bh0, AL0[ta], a, 0,0,0);
      a = __builtin_amdgcn_mfma_f32_16x16x32_bf16(bh1, AL1[ta], a, 0,0,0);
      int m = m0 + ta*16 + row;
      if (m < M){
        ushort4 v;
        v.x = f2bf(a[0]); v.y = f2bf(a[1]); v.z = f2bf(a[2]); v.w = f2bf(a[3]);
        *(ushort4*)(C + (size_t)m*4096 + n0 + tb*16 + quad*4) = v;
      }
    }
  }
}

// ---------------- edge gather: 2 edges/wave, no barriers, bf16 Q ----------------
template<int PASS>
__global__ __launch_bounds__(256) void k_edge_gather(const u16* __restrict__ Q,
    const float* __restrict__ hidden, int h0,
    const float* __restrict__ bterm, const int* __restrict__ srcS,
    const int* __restrict__ dstS,
    float* __restrict__ msg, float* __restrict__ agg, int E)
{
  __shared__ float hs[4][2][64];
  __shared__ float red[4][2][64];
  const int wv = threadIdx.x>>6, lane = threadIdx.x&63;
  const int ew0 = (blockIdx.x*4 + wv)*2;
  const bool v0 = (ew0 < E), v1 = (ew0+1 < E);
  const int e0 = v0 ? ew0 : 0;
  const int e1 = v1 ? ew0+1 : 0;
  const int s0 = srcS[e0], s1 = srcS[e1];
  hs[wv][0][lane] = hidden[(size_t)e0*128 + h0 + lane];
  hs[wv][1][lane] = hidden[(size_t)e1*128 + h0 + lane];
  // per-wave LDS only: in-wave lgkmcnt ordering suffices, no __syncthreads
  const int sg = lane>>4, oq = lane&15;
  const u16* q0 = Q + (size_t)s0*4096 + sg*64 + oq*4;
  const u16* q1 = Q + (size_t)s1*4096 + sg*64 + oq*4;
  float a00=0.f,a01=0.f,a02=0.f,a03=0.f;
  float a10=0.f,a11=0.f,a12=0.f,a13=0.f;
  #pragma unroll
  for (int j=0;j<16;j++){
    ushort4 qa = *(const ushort4*)(q0 + j*256);
    ushort4 qb = *(const ushort4*)(q1 + j*256);
    float h0v = hs[wv][0][j*4 + sg];
    float h1v = hs[wv][1][j*4 + sg];
    a00 = fmaf(h0v, bf2f(qa.x), a00); a01 = fmaf(h0v, bf2f(qa.y), a01);
    a02 = fmaf(h0v, bf2f(qa.z), a02); a03 = fmaf(h0v, bf2f(qa.w), a03);
    a10 = fmaf(h1v, bf2f(qb.x), a10); a11 = fmaf(h1v, bf2f(qb.y), a11);
    a12 = fmaf(h1v, bf2f(qb.z), a12); a13 = fmaf(h1v, bf2f(qb.w), a13);
  }
  a00 += __shfl_xor(a00,16); a00 += __shfl_xor(a00,32);
  a01 += __shfl_xor(a01,16); a01 += __shfl_xor(a01,32);
  a02 += __shfl_xor(a02,16); a02 += __shfl_xor(a02,32);
  a03 += __shfl_xor(a03,16); a03 += __shfl_xor(a03,32);
  a10 += __shfl_xor(a10,16); a10 += __shfl_xor(a10,32);
  a11 += __shfl_xor(a11,16); a11 += __shfl_xor(a11,32);
  a12 += __shfl_xor(a12,16); a12 += __shfl_xor(a12,32);
  a13 += __shfl_xor(a13,16); a13 += __shfl_xor(a13,32);
  if (lane < 16){
    float4 r0; r0.x=a00; r0.y=a01; r0.z=a02; r0.w=a03;
    float4 r1; r1.x=a10; r1.y=a11; r1.z=a12; r1.w=a13;
    *(float4*)&red[wv][0][lane*4] = r0;
    *(float4*)&red[wv][1][lane*4] = r1;
  }
  // in-wave lgkmcnt ordering; no barrier
  if (v0){
    float rv = red[wv][0][lane];
    if (PASS == 0) msg[(size_t)ew0*64 + lane] = bterm[(size_t)s0*64 + lane] + rv;
    else atomicAdd(&agg[(size_t)dstS[ew0]*64 + lane], msg[(size_t)ew0*64 + lane] + rv);
  }
  if (v1){
    float rv = red[wv][1][lane];
    if (PASS == 0) msg[(size_t)(ew0+1)*64 + lane] = bterm[(size_t)s1*64 + lane] + rv;
    else atomicAdd(&agg[(size_t)dstS[ew0+1]*64 + lane], msg[(size_t)(ew0+1)*64 + lane] + rv);
  }
}

// ---------------- agg-normalize + root + GRU + bf16 shadow + fused bterm ---------
__global__ __launch_bounds__(256) void k_node_update(const float* __restrict__ outOld,
    const float* __restrict__ agg, const float* __restrict__ deg,
    const float* __restrict__ rootT, const float* __restrict__ conv_b,
    const float* __restrict__ wihT, const float* __restrict__ whhT,
    const float* __restrict__ b_ih, const float* __restrict__ b_hh,
    const float* __restrict__ nn2_b,
    float* __restrict__ outNew, u16* __restrict__ outH, u16* __restrict__ outL,
    float* __restrict__ bterm, int N)
{
  __shared__ float hs[4][64];
  __shared__ float ms[4][64];
  int ln = threadIdx.x>>6, o = threadIdx.x&63;
  int n = blockIdx.x*4+ln;
  bool ok = (n<N);
  float h = ok ? outOld[(size_t)n*64+o] : 0.f;
  hs[ln][o] = h;
  __syncthreads();
  float root = 0.f;
  #pragma unroll 8
  for (int i=0;i<64;i++) root = fmaf(hs[ln][i], rootT[i*64+o], root);
  float d = ok ? fmaxf(deg[n], 1.f) : 1.f;
  float a = ok ? agg[(size_t)n*64+o]/d : 0.f;
  float m = fmaxf(a + root + conv_b[o], 0.f);
  ms[ln][o] = m;
  __syncthreads();
  float gir=b_ih[o], giz=b_ih[64+o], gin=b_ih[128+o];
  float ghr=b_hh[o], ghz=b_hh[64+o], ghn=b_hh[128+o];
  #pragma unroll 4
  for (int i=0;i<64;i++){
    float mi = ms[ln][i], hi = hs[ln][i];
    gir = fmaf(mi, wihT[i*192+o],      gir);
    giz = fmaf(mi, wihT[i*192+64+o],   giz);
    gin = fmaf(mi, wihT[i*192+128+o],  gin);
    ghr = fmaf(hi, whhT[i*192+o],      ghr);
    ghz = fmaf(hi, whhT[i*192+64+o],   ghz);
    ghn = fmaf(hi, whhT[i*192+128+o],  ghn);
  }
  float r = sigmoidf_(gir+ghr);
  float z = sigmoidf_(giz+ghz);
  float nn = tanhf(gin + r*ghn);
  if (ok){
    float v = (1.f-z)*nn + z*h;
    outNew[(size_t)n*64+o] = v;
    u16 hi16, lo16; split_bf(v, hi16, lo16);
    outH[(size_t)n*64+o] = hi16;
    outL[(size_t)n*64+o] = lo16;
    float bt = 0.f;
    #pragma unroll 8
    for (int i=0;i<64;i++) bt = fmaf(__shfl(v, i, 64), nn2_b[i*64+o], bt);
    bterm[(size_t)n*64+o] = bt;
  }
}

// ---------------- Set2Set (3 steps) + final MLP: LDS-staged, one block/graph -------
__global__ __launch_bounds__(256) void k_set2set(const float* __restrict__ out,
    const int* __restrict__ batch, int N,
    const float* __restrict__ lwihT, const float* __restrict__ lwhhT,
    const float* __restrict__ b_ih, const float* __restrict__ b_hh,
    const float* __restrict__ lin1T, const float* __restrict__ lin1_b,
    const float* __restrict__ lin2_w, const float* __restrict__ lin2_b,
    float* __restrict__ y)
{
  __shared__ float X[S2CAP][65];
  __shared__ float earr[S2CAP];
  __shared__ float qstar[128], hl[64], cl[64], g[256];
  __shared__ float rpart[4][64], spart[4], redm[4], zs[64];
  __shared__ int sb[2];
  const int tid = threadIdx.x;
  const int b = blockIdx.x;
  const int wid = tid>>6, lane = tid&63;
  if (tid < 128) qstar[tid] = 0.f;
  if (tid < 64){ hl[tid]=0.f; cl[tid]=0.f; }
  if (tid == 0){
    int lo=0, hi=N;
    while (lo<hi){ int mid=(lo+hi)>>1; if (batch[mid] < b) lo=mid+1; else hi=mid; }
    sb[0]=lo;
    int lo2=lo, hi2=N;
    while (lo2<hi2){ int mid=(lo2+hi2)>>1; if (batch[mid] < b+1) lo2=mid+1; else hi2=mid; }
    sb[1]=lo2;
  }
  __syncthreads();
  const int nlo = sb[0], nhi = sb[1], nn = nhi - nlo;
  const bool single = (nn <= S2CAP);
  if (single){
    for (int idx = tid; idx < nn*64; idx += 256){
      X[idx>>6][idx&63] = out[(size_t)(nlo + (idx>>6))*64 + (idx&63)];
    }
  }
  __syncthreads();

  for (int step=0; step<3; step++){
    float gs = b_ih[tid] + b_hh[tid];
    for (int j=0;j<128;j++) gs = fmaf(qstar[j], lwihT[j*256+tid], gs);
    for (int j=0;j<64;j++)  gs = fmaf(hl[j],    lwhhT[j*256+tid], gs);
    g[tid] = gs;
    __syncthreads();
    if (tid < 64){
      float ig = sigmoidf_(g[tid]);
      float fg = sigmoidf_(g[64+tid]);
      float gg = tanhf(g[128+tid]);
      float og = sigmoidf_(g[192+tid]);
      float c = fg*cl[tid] + ig*gg;
      cl[tid] = c;
      hl[tid] = og*tanhf(c);
    }
    __syncthreads();

    if (single){
      float lm = -INFINITY;
      for (int n = tid; n < nn; n += 256){
        float acc = 0.f;
        #pragma unroll 8
        for (int d=0; d<64; d++) acc = fmaf(X[n][d], hl[d], acc);
        earr[n] = acc;
        lm = fmaxf(lm, acc);
      }
      lm = fmaxf(lm, __shfl_xor(lm,1));  lm = fmaxf(lm, __shfl_xor(lm,2));
      lm = fmaxf(lm, __shfl_xor(lm,4));  lm = fmaxf(lm, __shfl_xor(lm,8));
      lm = fmaxf(lm, __shfl_xor(lm,16)); lm = fmaxf(lm, __shfl_xor(lm,32));
      if (lane==0) redm[wid] = lm;
      __syncthreads();
      if (tid==0) redm[0] = fmaxf(fmaxf(redm[0],redm[1]), fmaxf(redm[2],redm[3]));
      __syncthreads();
      const float gmax = redm[0];
      float ls = 0.f;
      for (int n = tid; n < nn; n += 256){
        float a = expf(earr[n] - gmax);
        earr[n] = a;
        ls += a;
      }
      ls += __shfl_xor(ls,1);  ls += __shfl_xor(ls,2);  ls += __shfl_xor(ls,4);
      ls += __shfl_xor(ls,8);  ls += __shfl_xor(ls,16); ls += __shfl_xor(ls,32);
      if (lane==0) spart[wid] = ls;
      __syncthreads();
      float racc = 0.f;
      for (int n = wid; n < nn; n += 4) racc = fmaf(earr[n], X[n][lane], racc);
      rpart[wid][lane] = racc;
      __syncthreads();
      if (tid < 64){
        float r = rpart[0][tid]+rpart[1][tid]+rpart[2][tid]+rpart[3][tid];
        float s = spart[0]+spart[1]+spart[2]+spart[3];
        qstar[tid] = hl[tid];
        qstar[64+tid] = (nn>0) ? r/s : 0.f;
      }
      __syncthreads();
    } else {
      float qv = hl[lane];
      float lm = -INFINITY;
      for (int n = nlo + wid; n < nhi; n += 4){
        float p = out[(size_t)n*64 + lane]*qv;
        p += __shfl_xor(p,1); p += __shfl_xor(p,2); p += __shfl_xor(p,4);
        p += __shfl_xor(p,8); p += __shfl_xor(p,16); p += __shfl_xor(p,32);
        lm = fmaxf(lm, p);
      }
      if (lane==0) redm[wid] = lm;
      __syncthreads();
      if (tid==0) redm[0] = fmaxf(fmaxf(redm[0],redm[1]), fmaxf(redm[2],redm[3]));
      __syncthreads();
      float gmax = redm[0];
      float sw = 0.f, racc = 0.f;
      for (int n = nlo + wid; n < nhi; n += 4){
        float ol = out[(size_t)n*64 + lane];
        float p = ol*qv;
        p += __shfl_xor(p,1); p += __shfl_xor(p,2); p += __shfl_xor(p,4);
        p += __shfl_xor(p,8); p += __shfl_xor(p,16); p += __shfl_xor(p,32);
        float a = expf(p - gmax);
        sw += a;
        racc = fmaf(a, ol, racc);
      }
      rpart[wid][lane] = racc;
      if (lane==0) spart[wid] = sw;
      __syncthreads();
      if (tid < 64){
        float r = rpart[0][tid]+rpart[1][tid]+rpart[2][tid]+rpart[3][tid];
        float s = spart[0]+spart[1]+spart[2]+spart[3];
        qstar[tid] = hl[tid];
        qstar[64+tid] = (nn>0) ? r/s : 0.f;
      }
      __syncthreads();
    }
  }
  if (tid < 64){
    float acc = lin1_b[tid];
    for (int j=0;j<128;j++) acc = fmaf(qstar[j], lin1T[j*64+tid], acc);
    zs[tid] = fmaxf(acc, 0.f);
  }
  __syncthreads();
  if (tid < 64){
    float v = zs[lane]*lin2_w[lane];
    v += __shfl_xor(v,1); v += __shfl_xor(v,2); v += __shfl_xor(v,4);
    v += __shfl_xor(v,8); v += __shfl_xor(v,16); v += __shfl_xor(v,32);
    if (lane==0) y[b] = v + lin2_b[0];
  }
}

extern "C" void kernel_launch(void* const* d_in, const int* in_sizes, int n_in,
                              void* d_out, int out_size, void* d_ws, size_t ws_size,
                              hipStream_t stream)
{
  const float* x      = (const float*)d_in[0];
  const float* eattr  = (const float*)d_in[1];
  const float* lin0_w = (const float*)d_in[2];
  const float* lin0_b = (const float*)d_in[3];
  const float* nn1_w  = (const float*)d_in[4];
  const float* nn1_b  = (const float*)d_in[5];
  const float* nn2_w  = (const float*)d_in[6];
  const float* nn2_b  = (const float*)d_in[7];
  const float* root_w = (const float*)d_in[8];
  const float* conv_b = (const float*)d_in[9];
  const float* gwih   = (const float*)d_in[10];
  const float* gwhh   = (const float*)d_in[11];
  const float* gbih   = (const float*)d_in[12];
  const float* gbhh   = (const float*)d_in[13];
  const float* lwih   = (const float*)d_in[14];
  const float* lwhh   = (const float*)d_in[15];
  const float* lbih   = (const float*)d_in[16];
  const float* lbhh   = (const float*)d_in[17];
  const float* lin1_w = (const float*)d_in[18];
  const float* lin1_b = (const float*)d_in[19];
  const float* lin2_w = (const float*)d_in[20];
  const float* lin2_b = (const float*)d_in[21];
  const int*   eidx   = (const int*)d_in[22];
  const int*   batch  = (const int*)d_in[23];

  const int N = in_sizes[0]/FN;
  const int E = in_sizes[1]/FE;
  const int* srcI = eidx;
  const int* dstI = eidx + E;

  char* w = (char*)d_ws;
  size_t off = 0;
  auto alloc = [&](size_t bytes)->char* {
    char* p = w + off;
    off = (off + bytes + 255) & ~(size_t)255;
    return p;
  };
  float* degw  = (float*)alloc((size_t)N*4);
  int*   scnt  = (int*)alloc((size_t)N*4);
  int*   starts= (int*)alloc((size_t)(N+1)*4);
  int*   cursor= (int*)alloc((size_t)N*4);
  int*   bsum  = (int*)alloc((size_t)256*4);
  int*   sortedE=(int*)alloc((size_t)E*4);
  int*   srcS  = (int*)alloc((size_t)E*4);
  int*   dstS  = (int*)alloc((size_t)E*4);
  float* outA  = (float*)alloc((size_t)N*64*4);
  float* outB  = (float*)alloc((size_t)N*64*4);
  u16*   outAH = (u16*)alloc((size_t)N*64*2);
  u16*   outAL = (u16*)alloc((size_t)N*64*2);
  u16*   outBH = (u16*)alloc((size_t)N*64*2);
  u16*   outBL = (u16*)alloc((size_t)N*64*2);
  float* agg   = (float*)alloc((size_t)N*64*4);
  float* bterm = (float*)alloc((size_t)N*64*4);
  float* hidden= (float*)alloc((size_t)E*128*4);
  float* msg   = (float*)alloc((size_t)E*64*4);
  u16*   B2hT  = (u16*)alloc((size_t)524288*2);
  u16*   B2lT  = (u16*)alloc((size_t)524288*2);
  u16*   BT1h  = (u16*)alloc((size_t)8192*2);
  u16*   BT1l  = (u16*)alloc((size_t)8192*2);
  float* lin0T = (float*)alloc((size_t)92*64*4);
  float* nn1T  = (float*)alloc((size_t)41*128*4);
  float* rootT = (float*)alloc((size_t)64*64*4);
  float* wihT  = (float*)alloc((size_t)64*192*4);
  float* whhT  = (float*)alloc((size_t)64*192*4);
  float* lwihT = (float*)alloc((size_t)128*256*4);
  float* lwhhT = (float*)alloc((size_t)64*256*4);
  float* lin1T = (float*)alloc((size_t)128*64*4);
  u16*   Q     = (u16*)alloc((size_t)N*4096*2);   // one 64-h chunk, bf16: [n][h*64+o]
  // eaH/eaL overlay Q's buffer: consumed by k_edge_mlp_mfma before first qgemm write
  u16* eaH = (u16*)Q;
  u16* eaL = eaH + (size_t)E*64;

  const int NB = (N+255)/256;

  hipMemsetAsync(degw, 0, (size_t)N*4, stream);
  hipMemsetAsync(scnt, 0, (size_t)N*4, stream);
  k_pack<<<(97152+255)/256, 256, 0, stream>>>(lin0_w, nn1_w, root_w, gwih, gwhh,
      lwih, lwhh, lin1_w, lin0T, nn1T, rootT, wihT, whhT, lwihT, lwhhT, lin1T);
  k_pack_b2<<<524288/256, 256, 0, stream>>>(nn2_w, B2hT, B2lT);
  k_pack_b1<<<8192/256, 256, 0, stream>>>(nn1_w, BT1h, BT1l);
  k_node_mlp<<<(N+3)/4, 256, 0, stream>>>(x, lin0T, lin0_b, nn2_b, outA, outAH, outAL, bterm, N);
  k_count<<<(E+255)/256, 256, 0, stream>>>(dstI, srcI, degw, scnt, E);
  k_scan1<<<NB, 256, 0, stream>>>(scnt, starts, bsum, N);
  k_scan2<<<1, 256, 0, stream>>>(bsum, NB);
  k_scan3<<<NB, 256, 0, stream>>>(starts, cursor, bsum, N, E);
  k_sort<<<(E+255)/256, 256, 0, stream>>>(srcI, dstI, cursor, sortedE, srcS, dstS, E);
  k_split_ea<<<((size_t)E*64+255)/256, 256, 0, stream>>>(eattr, sortedE, eaH, eaL, E);
  k_edge_mlp_mfma<<<(E+127)/128, 256, 0, stream>>>(eaH, eaL, BT1h, BT1l, nn1_b, hidden, E);

  float* cur = outA; float* nxt = outB;
  u16* curH = outAH; u16* curL = outAL;
  u16* nxtH = outBH; u16* nxtL = outBL;
  const dim3 qgrid(16, (N+63)/64);
  const int gatherGx = (E+7)/8;
  for (int conv=0; conv<2; conv++){
    hipMemsetAsync(agg, 0, (size_t)N*64*4, stream);
    // chunk 0 (h in [0,64))
    k_qgemm_mfma<<<qgrid, 256, 0, stream>>>(curH, curL, B2hT, B2lT, Q, N);
    k_edge_gather<0><<<gatherGx, 256, 0, stream>>>(Q, hidden, 0, bterm, srcS, dstS, msg, agg, E);
    // chunk 1 (h in [64,128))
    k_qgemm_mfma<<<qgrid, 256, 0, stream>>>(curH, curL, B2hT + 262144, B2lT + 262144, Q, N);
    k_edge_gather<1><<<gatherGx, 256, 0, stream>>>(Q, hidden, 64, bterm, srcS, dstS, msg, agg, E);
    k_node_update<<<(N+3)/4, 256, 0, stream>>>(cur, agg, degw, rootT, conv_b,
        wihT, whhT, gbih, gbhh, nn2_b, nxt, nxtH, nxtL, bterm, N);
    float* t = cur; cur = nxt; nxt = t;
    u16* th = curH; curH = nxtH; nxtH = th;
    u16* tl = curL; curL = nxtL; nxtL = tl;
  }

  k_set2set<<<128, 256, 0, stream>>>(cur, batch, N, lwihT, lwhhT, lbih, lbhh,
      lin1T, lin1_b, lin2_w, lin2_b, (float*)d_out);
}